// Round 12
// baseline (881.415 us; speedup 1.0000x reference)
//
#include <hip/hip_runtime.h>
#include <hip/hip_bf16.h>

#define NN 50000
#define NE 800000
#define EPSV 1e-5f
#define NB 49   // scan blocks: ceil(NN/1024)

typedef _Float16 h8 __attribute__((ext_vector_type(8)));
typedef _Float16 h4 __attribute__((ext_vector_type(4)));
typedef float    f4 __attribute__((ext_vector_type(4)));

// ---------------- graph preprocessing ----------------

__global__ void k_deg(const int* __restrict__ dst, int* __restrict__ deg){
  int e = blockIdx.x*blockDim.x + threadIdx.x;
  if(e < NE) atomicAdd(&deg[dst[e]], 1);
}

__global__ void k_logdeg(const int* __restrict__ deg, float* __restrict__ logdeg,
                         float* __restrict__ dsum){
  int i = blockIdx.x*blockDim.x + threadIdx.x;
  float v = 0.f;
  if(i < NN){ v = log1pf((float)deg[i]); logdeg[i] = v; }
  __shared__ float sh[256];
  sh[threadIdx.x] = v; __syncthreads();
  for(int off=128; off>0; off>>=1){
    if(threadIdx.x < off) sh[threadIdx.x] += sh[threadIdx.x+off];
    __syncthreads();
  }
  if(threadIdx.x == 0) atomicAdd(dsum, sh[0]);
}

__global__ void k_scalers(const float* __restrict__ logdeg, const float* __restrict__ dsum,
                          float* __restrict__ amp, float* __restrict__ att){
  int i = blockIdx.x*blockDim.x + threadIdx.x;
  if(i >= NN) return;
  float delta = dsum[0] / (float)NN;
  float ld = logdeg[i];
  amp[i] = ld / delta;
  att[i] = (ld > 0.f) ? (delta / fmaxf(ld, 1e-6f)) : 1.f;
}

// 3-phase parallel exclusive scan of deg -> rowptr (+cursor copy)
__global__ void k_scan1(const int* __restrict__ deg, int* __restrict__ rowptr,
                        int* __restrict__ bsum){
  __shared__ int buf[1024];
  int tid = threadIdx.x;
  int i = blockIdx.x*1024 + tid;
  int v = (i < NN) ? deg[i] : 0;
  buf[tid] = v; __syncthreads();
  for(int off=1; off<1024; off<<=1){
    int t = (tid >= off) ? buf[tid-off] : 0;
    __syncthreads();
    buf[tid] += t;
    __syncthreads();
  }
  if(i < NN) rowptr[i] = buf[tid] - v;
  if(tid == 1023) bsum[blockIdx.x] = buf[1023];
}

__global__ void k_scan2(int* __restrict__ bsum){
  if(threadIdx.x == 0){
    int s = 0;
    for(int b = 0; b < NB; b++){ int t = bsum[b]; bsum[b] = s; s += t; }
    bsum[NB] = s;
  }
}

__global__ void k_scan3(int* __restrict__ rowptr, int* __restrict__ cursor,
                        const int* __restrict__ bsum){
  int i = blockIdx.x*256 + threadIdx.x;
  if(i < NN){
    int v = rowptr[i] + bsum[i >> 10];
    rowptr[i] = v; cursor[i] = v;
  }
  if(i == NN) rowptr[NN] = bsum[NB];
}

__global__ void k_fill(const int* __restrict__ src, const int* __restrict__ dst,
                       int* __restrict__ cursor, int* __restrict__ colidx){
  int e = blockIdx.x*blockDim.x + threadIdx.x;
  if(e < NE){
    int pos = atomicAdd(&cursor[dst[e]], 1);
    colidx[pos] = src[e];
  }
}

__global__ void k_cvtx(const float* __restrict__ x, _Float16* __restrict__ hA){
  int i = blockIdx.x*256 + threadIdx.x;
  if(i < NN*64) hA[i] = (_Float16)x[i];
}

// ---------------- one-pass per-node aggregation (4 cols/lane, 8 B loads) ----------------
// aggs[chunk][n*256 + {0,64,128,192} + cl] = mean|min|max|std

__global__ __launch_bounds__(256) void k_agg4(
    const _Float16* __restrict__ h, int d,
    const int* __restrict__ rowptr, const int* __restrict__ colidx,
    _Float16* __restrict__ aggs, size_t aggN)
{
  int wv = threadIdx.x >> 6, lane = threadIdx.x & 63;
  int lpn = d >> 2;                 // lanes per node: 16/32/64
  int npw = 64 / lpn;               // nodes per wave: 4/2/1
  int n = blockIdx.x*(npw*4) + wv*npw + (lane / lpn);
  int c = (lane % lpn) * 4;         // 4 adjacent feature cols
  if(n >= NN) return;
  int beg = rowptr[n], end = rowptr[n+1];
  const _Float16* hp = h + c;

  float s0=0,s1=0,s2=0,s3=0, q0=0,q1=0,q2=0,q3=0;
  float mn0=INFINITY,mn1=INFINITY,mn2=INFINITY,mn3=INFINITY;
  float mx0=-INFINITY,mx1=-INFINITY,mx2=-INFINITY,mx3=-INFINITY;

#define ACC4(v) { float a0=(float)(v)[0],a1=(float)(v)[1],a2=(float)(v)[2],a3=(float)(v)[3]; \
    s0+=a0; q0+=a0*a0; mn0=fminf(mn0,a0); mx0=fmaxf(mx0,a0); \
    s1+=a1; q1+=a1*a1; mn1=fminf(mn1,a1); mx1=fmaxf(mx1,a1); \
    s2+=a2; q2+=a2*a2; mn2=fminf(mn2,a2); mx2=fmaxf(mx2,a2); \
    s3+=a3; q3+=a3*a3; mn3=fminf(mn3,a3); mx3=fmaxf(mx3,a3); }

  int e = beg;
  for(; e+4 <= end; e+=4){
    int i0=colidx[e], i1=colidx[e+1], i2=colidx[e+2], i3=colidx[e+3];
    h4 v0 = *(const h4*)(hp + (size_t)i0*d);
    h4 v1 = *(const h4*)(hp + (size_t)i1*d);
    h4 v2 = *(const h4*)(hp + (size_t)i2*d);
    h4 v3 = *(const h4*)(hp + (size_t)i3*d);
    ACC4(v0) ACC4(v1) ACC4(v2) ACC4(v3)
  }
  for(; e < end; e++){
    h4 v = *(const h4*)(hp + (size_t)colidx[e]*d);
    ACC4(v)
  }
#undef ACC4

  float cnt = (end>beg) ? (float)(end-beg) : 1.f;
  float me0=s0/cnt, me1=s1/cnt, me2=s2/cnt, me3=s3/cnt;
  float sd0 = sqrtf(fmaxf(q0/cnt - me0*me0, 0.f) + EPSV);
  float sd1 = sqrtf(fmaxf(q1/cnt - me1*me1, 0.f) + EPSV);
  float sd2 = sqrtf(fmaxf(q2/cnt - me2*me2, 0.f) + EPSV);
  float sd3 = sqrtf(fmaxf(q3/cnt - me3*me3, 0.f) + EPSV);
  if(end <= beg){ mn0=mn1=mn2=mn3=0.f; mx0=mx1=mx2=mx3=0.f; }

  _Float16* dst = aggs + (size_t)(c>>6)*aggN + (size_t)n*256 + (c & 63);
  h4 om = {(_Float16)me0,(_Float16)me1,(_Float16)me2,(_Float16)me3};
  h4 on = {(_Float16)mn0,(_Float16)mn1,(_Float16)mn2,(_Float16)mn3};
  h4 ox = {(_Float16)mx0,(_Float16)mx1,(_Float16)mx2,(_Float16)mx3};
  h4 os = {(_Float16)sd0,(_Float16)sd1,(_Float16)sd2,(_Float16)sd3};
  *(h4*)(dst)       = om;
  *(h4*)(dst + 64)  = on;
  *(h4*)(dst + 128) = ox;
  *(h4*)(dst + 192) = os;
}

// ---------------- fused W pre-pack (all layers/chunks, one kernel) ----------------
// Per chunk slab: Wp[kb=K/32][nt=o/16][lane=64][j=8]; row perm: k<64 -> j0+k ;
// [64,320)->(1+q)d+j0+r ; [320,576)->(5+q)d+j0+r ; [576,832)->(9+q)d+j0+r

struct PackJob { const float* W; _Float16* dst; int d, o, j0, start; };
struct PackArgs { PackJob job[9]; int total; };

__global__ void k_pack_all(PackArgs a){
  int idx = blockIdx.x*256 + threadIdx.x;
  if(idx >= a.total) return;
  int ji = 0;
  while(ji < 8 && idx >= a.job[ji+1].start) ji++;
  PackJob J = a.job[ji];
  int rel = idx - J.start;
  int j    = rel & 7;
  int lane = (rel >> 3) & 63;
  int rem  = rel >> 9;
  int ntiles = J.o >> 4;
  int kb = rem / ntiles;
  int nt = rem - kb*ntiles;
  int k = kb*32 + (lane>>4)*8 + j;
  int n = nt*16 + (lane&15);
  int srcrow;
  if(k < 64)       srcrow = J.j0 + k;
  else if(k < 320){ int t=k-64;  srcrow = (1+(t>>6))*J.d + J.j0 + (t&63); }
  else if(k < 576){ int t=k-320; srcrow = (5+(t>>6))*J.d + J.j0 + (t&63); }
  else            { int t=k-576; srcrow = (9+(t>>6))*J.d + J.j0 + (t&63); }
  J.dst[rel] = (_Float16)J.W[(size_t)srcrow*J.o + n];
}

// ---------------- fused MFMA layer GEMM (16x64 wave tile) ----------------
// One dispatch per layer; K (13d) accumulated in registers across chunks.
// Wave tile = 16 rows x 64 cols (nn=4); block = 4 waves = 64 rows.
// Column-blocks = o/64 (<=2) so L3 dedups A/aggs re-reads (r11 lesson);
// waves = (NN/16)*(o/64) = 2x r9's count (r11's occupancy lesson).
// Epilogue: +bias, ReLU, fp16 store.

__global__ __launch_bounds__(256) void k_mfma_fused(
    const _Float16* __restrict__ hA, int d, int nch,
    const _Float16* __restrict__ aggs,          // [nch][NN][256]
    const float* __restrict__ amp, const float* __restrict__ att,
    const _Float16* __restrict__ Wp, int o,     // [nch][832*o]
    const float* __restrict__ bias,
    _Float16* __restrict__ out)                 // [NN][o], relu'd
{
  int tid  = threadIdx.x;
  int wv   = tid >> 6;
  int lane = tid & 63;
  int mi   = lane & 15;
  int q    = lane >> 4;
  int m0   = blockIdx.y * 64 + wv * 16;
  int c0   = blockIdx.x * 64;
  int ntiles = o >> 4;
  int nt0  = blockIdx.x * 4;

  int mrow = min(m0 + mi, NN-1);
  _Float16 am16 = (_Float16)amp[mrow];
  _Float16 at16 = (_Float16)att[mrow];
  const _Float16* hAb = hA + (size_t)mrow*d + q*8;
  const _Float16* agb = aggs + (size_t)mrow*256 + q*8;

  f4 acc[4] = {};
  const size_t aggN = (size_t)NN*256;

  for(int c = 0; c < nch; c++){
    const _Float16* Wpc = Wp + (size_t)c*832*o;
    auto bfrag = [&](int kb, int nn) -> h8 {
      return *(const h8*)(Wpc + (((size_t)kb*ntiles + nt0 + nn)*64 + lane)*8);
    };

    // ---- A fragments for this chunk (prefetch) ----
    h8 ax[2];
    h8 ag[8];
    #pragma unroll
    for(int kb = 0; kb < 2; kb++)
      ax[kb] = *(const h8*)(hAb + c*64 + kb*32);
    #pragma unroll
    for(int idx = 0; idx < 8; idx++)
      ag[idx] = *(const h8*)(agb + (size_t)c*aggN + idx*32);

    // ---- phase X: hA chunk, kb = 0,1 ----
    #pragma unroll
    for(int kb = 0; kb < 2; kb++)
      #pragma unroll
      for(int nn = 0; nn < 4; nn++)
        acc[nn] = __builtin_amdgcn_mfma_f32_16x16x32_f16(ax[kb], bfrag(kb,nn), acc[nn], 0,0,0);

    // ---- aggs phases: plain / amp-scaled / att-scaled ----
    #pragma unroll
    for(int idx = 0; idx < 8; idx++){
      h8 apl = ag[idx];
      h8 aam = apl * am16;
      h8 aat = apl * at16;
      #pragma unroll
      for(int nn = 0; nn < 4; nn++){
        acc[nn] = __builtin_amdgcn_mfma_f32_16x16x32_f16(apl, bfrag(2+idx,  nn), acc[nn], 0,0,0);
        acc[nn] = __builtin_amdgcn_mfma_f32_16x16x32_f16(aam, bfrag(10+idx, nn), acc[nn], 0,0,0);
        acc[nn] = __builtin_amdgcn_mfma_f32_16x16x32_f16(aat, bfrag(18+idx, nn), acc[nn], 0,0,0);
      }
    }
  }

  // ---- epilogue: +bias, ReLU, fp16 store. D col = lane&15, row = q*4+reg ----
  #pragma unroll
  for(int nn = 0; nn < 4; nn++){
    int n = c0 + nn*16 + mi;
    float bv = bias[n];
    #pragma unroll
    for(int r = 0; r < 4; r++){
      int m = m0 + q*4 + r;
      if(m < NN)
        out[(size_t)m*o + n] = (_Float16)fmaxf(bv + acc[nn][r], 0.f);
    }
  }
}

// ---------------- BatchNorm (input already relu'd, fp16) ----------------

__global__ __launch_bounds__(256) void k_bn_stats(const _Float16* __restrict__ H, int dout,
                                                  float* __restrict__ colsum, float* __restrict__ colss){
  int tid = threadIdx.x;
  int gid = blockIdx.x*256 + tid;
  int stride = gridDim.x*256;
  int total = NN * dout;
  float s = 0.f, ss = 0.f;
  for(int i = gid; i < total; i += stride){
    float v = (float)H[i];
    s += v; ss += v*v;
  }
  __shared__ float shs[256], shss[256];
  shs[tid] = s; shss[tid] = ss;
  __syncthreads();
  if(tid < dout){
    float ts = 0.f, tss = 0.f;
    for(int i = tid; i < 256; i += dout){ ts += shs[i]; tss += shss[i]; }
    atomicAdd(&colsum[tid], ts);
    atomicAdd(&colss[tid], tss);
  }
}

__global__ void k_bn_apply(const _Float16* __restrict__ H, int dout,
                           const float* __restrict__ colsum, const float* __restrict__ colss,
                           const float* __restrict__ gamma, const float* __restrict__ beta,
                           _Float16* __restrict__ out){
  int i = blockIdx.x*blockDim.x + threadIdx.x;
  int total = NN * dout;
  if(i >= total) return;
  int c = i & (dout - 1);
  float mean = colsum[c] / (float)NN;
  float var  = colss[c] / (float)NN - mean*mean;
  float inv  = rsqrtf(fmaxf(var, 0.f) + EPSV);
  float v = (float)H[i];
  out[i] = (_Float16)((v - mean) * inv * gamma[c] + beta[c]);
}

// ---------------- classifier ----------------

__global__ __launch_bounds__(256) void k_cls(const _Float16* __restrict__ h,
    const float* __restrict__ Wc, const float* __restrict__ bc,
    float* __restrict__ out){
  __shared__ float w[640];
  __shared__ float bb[16];
  int tid = threadIdx.x;
  for(int i = tid; i < 640; i += 256) w[i] = Wc[i];
  if(tid < 10) bb[tid] = bc[tid];
  __syncthreads();
  int idx = blockIdx.x*256 + tid;
  int n = idx >> 4;
  int c = idx & 15;
  if(n < NN && c < 10){
    float acc = bb[c];
    const _Float16* hp = h + (size_t)n*64;
    #pragma unroll
    for(int k = 0; k < 64; k++) acc += (float)hp[k] * w[k*10 + c];
    out[(size_t)n*10 + c] = acc;
  }
}

// ---------------- launch ----------------

extern "C" void kernel_launch(void* const* d_in, const int* in_sizes, int n_in,
                              void* d_out, int out_size, void* d_ws, size_t ws_size,
                              hipStream_t stream){
  const float* x = (const float*)d_in[0];
  const int* edge = (const int*)d_in[1];
  const int* esrc = edge;
  const int* edst = edge + NE;
  const float* W[4]  = {(const float*)d_in[2],  (const float*)d_in[6],
                        (const float*)d_in[10], (const float*)d_in[14]};
  const float* bb[4] = {(const float*)d_in[3],  (const float*)d_in[7],
                        (const float*)d_in[11], (const float*)d_in[15]};
  const float* gm[4] = {(const float*)d_in[4],  (const float*)d_in[8],
                        (const float*)d_in[12], (const float*)d_in[16]};
  const float* bt[4] = {(const float*)d_in[5],  (const float*)d_in[9],
                        (const float*)d_in[13], (const float*)d_in[17]};
  const float* Wc = (const float*)d_in[18];
  const float* bc = (const float*)d_in[19];
  (void)in_sizes; (void)n_in; (void)out_size; (void)ws_size;

  // workspace carve (~158 MB; proven-safe envelope)
  char* p = (char*)d_ws;
  auto alloc = [&](size_t bytes)->char*{
    char* r = p; p += (bytes + 255) & ~(size_t)255; return r;
  };
  _Float16* hA   = (_Float16*)alloc((size_t)NN*256*2);   // 25.6 MB
  _Float16* hB   = (_Float16*)alloc((size_t)NN*256*2);   // 25.6 MB (relu'd, fp16)
  _Float16* aggs = (_Float16*)alloc((size_t)4*NN*256*2); // 102.4 MB: [chunk][N][256]
  int*   deg    = (int*)  alloc((size_t)NN*4);
  float* logdeg = (float*)alloc((size_t)NN*4);
  float* amp    = (float*)alloc((size_t)NN*4);
  float* att    = (float*)alloc((size_t)NN*4);
  int*   rowptr = (int*)  alloc((size_t)(NN+1)*4);
  int*   cursor = (int*)  alloc((size_t)NN*4);
  int*   colidx = (int*)  alloc((size_t)NE*4);
  int*   bsum   = (int*)  alloc((size_t)(NB+1)*4);
  float* colsumL= (float*)alloc(4*256*4);   // per-layer BN partials
  float* colssL = (float*)alloc(4*256*4);
  float* dsum   = (float*)alloc(256);

  const int din[4]  = {64, 128, 256, 128};
  const int dto[4]  = {128, 256, 128, 64};
  const size_t aggN = (size_t)NN*256;      // halves per chunk slab
  _Float16* WpL[4];
  PackArgs pa; int pj = 0, poff = 0;
  for(int l = 0; l < 4; l++){
    int nch = din[l]/64;
    WpL[l] = (_Float16*)alloc((size_t)nch*832*dto[l]*2);
    for(int c = 0; c < nch; c++){
      pa.job[pj] = { W[l], WpL[l] + (size_t)c*832*dto[l], din[l], dto[l], c*64, poff };
      poff += 832*dto[l]; pj++;
    }
  }
  pa.total = poff;

  hipMemsetAsync(deg, 0, (size_t)NN*4, stream);
  hipMemsetAsync(dsum, 0, 4, stream);
  hipMemsetAsync(colsumL, 0, 4*256*4, stream);
  hipMemsetAsync(colssL,  0, 4*256*4, stream);

  k_pack_all<<<(pa.total+255)/256, 256, 0, stream>>>(pa);
  k_deg     <<<(NE+255)/256, 256, 0, stream>>>(edst, deg);
  k_logdeg  <<<(NN+255)/256, 256, 0, stream>>>(deg, logdeg, dsum);
  k_scalers <<<(NN+255)/256, 256, 0, stream>>>(logdeg, dsum, amp, att);
  k_scan1   <<<NB, 1024, 0, stream>>>(deg, rowptr, bsum);
  k_scan2   <<<1, 64, 0, stream>>>(bsum);
  k_scan3   <<<(NN+256)/256, 256, 0, stream>>>(rowptr, cursor, bsum);
  k_fill    <<<(NE+255)/256, 256, 0, stream>>>(esrc, edst, cursor, colidx);
  k_cvtx    <<<(NN*64+255)/256, 256, 0, stream>>>(x, hA);

  for(int l = 0; l < 4; l++){
    int d = din[l], o = dto[l];
    int nch = d / 64;
    int npb = (64 / (d >> 2)) * 4;          // nodes per block in k_agg4
    k_agg4<<<(NN+npb-1)/npb, 256, 0, stream>>>(hA, d, rowptr, colidx, aggs, aggN);
    dim3 g(o/64, (NN+63)/64);
    k_mfma_fused<<<g, 256, 0, stream>>>(hA, d, nch, aggs, amp, att, WpL[l], o, bb[l], hB);
    k_bn_stats<<<256, 256, 0, stream>>>(hB, o, colsumL + l*256, colssL + l*256);
    k_bn_apply<<<(NN*o+255)/256, 256, 0, stream>>>(hB, o, colsumL + l*256, colssL + l*256,
                                                   gm[l], bt[l], hA);
  }
  k_cls<<<(NN*16+255)/256, 256, 0, stream>>>(hA, Wc, bc, (float*)d_out);
}

// Round 13
// 804.381 us; speedup vs baseline: 1.0958x; 1.0958x over previous
//
#include <hip/hip_runtime.h>
#include <hip/hip_bf16.h>

#define NN 50000
#define NE 800000
#define EPSV 1e-5f
#define NB 49   // scan blocks: ceil(NN/1024)

typedef _Float16 h8 __attribute__((ext_vector_type(8)));
typedef _Float16 h4 __attribute__((ext_vector_type(4)));
typedef float    f4 __attribute__((ext_vector_type(4)));

// ---------------- graph preprocessing ----------------

__global__ void k_deg(const int* __restrict__ dst, int* __restrict__ deg){
  int e = blockIdx.x*blockDim.x + threadIdx.x;
  if(e < NE) atomicAdd(&deg[dst[e]], 1);
}

__global__ void k_logdeg(const int* __restrict__ deg, float* __restrict__ logdeg,
                         float* __restrict__ dsum){
  int i = blockIdx.x*blockDim.x + threadIdx.x;
  float v = 0.f;
  if(i < NN){ v = log1pf((float)deg[i]); logdeg[i] = v; }
  __shared__ float sh[256];
  sh[threadIdx.x] = v; __syncthreads();
  for(int off=128; off>0; off>>=1){
    if(threadIdx.x < off) sh[threadIdx.x] += sh[threadIdx.x+off];
    __syncthreads();
  }
  if(threadIdx.x == 0) atomicAdd(dsum, sh[0]);
}

__global__ void k_scalers(const float* __restrict__ logdeg, const float* __restrict__ dsum,
                          float* __restrict__ amp, float* __restrict__ att){
  int i = blockIdx.x*blockDim.x + threadIdx.x;
  if(i >= NN) return;
  float delta = dsum[0] / (float)NN;
  float ld = logdeg[i];
  amp[i] = ld / delta;
  att[i] = (ld > 0.f) ? (delta / fmaxf(ld, 1e-6f)) : 1.f;
}

// 3-phase parallel exclusive scan of deg -> rowptr (+cursor copy)
__global__ void k_scan1(const int* __restrict__ deg, int* __restrict__ rowptr,
                        int* __restrict__ bsum){
  __shared__ int buf[1024];
  int tid = threadIdx.x;
  int i = blockIdx.x*1024 + tid;
  int v = (i < NN) ? deg[i] : 0;
  buf[tid] = v; __syncthreads();
  for(int off=1; off<1024; off<<=1){
    int t = (tid >= off) ? buf[tid-off] : 0;
    __syncthreads();
    buf[tid] += t;
    __syncthreads();
  }
  if(i < NN) rowptr[i] = buf[tid] - v;
  if(tid == 1023) bsum[blockIdx.x] = buf[1023];
}

__global__ void k_scan2(int* __restrict__ bsum){
  if(threadIdx.x == 0){
    int s = 0;
    for(int b = 0; b < NB; b++){ int t = bsum[b]; bsum[b] = s; s += t; }
    bsum[NB] = s;
  }
}

__global__ void k_scan3(int* __restrict__ rowptr, int* __restrict__ cursor,
                        const int* __restrict__ bsum){
  int i = blockIdx.x*256 + threadIdx.x;
  if(i < NN){
    int v = rowptr[i] + bsum[i >> 10];
    rowptr[i] = v; cursor[i] = v;
  }
  if(i == NN) rowptr[NN] = bsum[NB];
}

__global__ void k_fill(const int* __restrict__ src, const int* __restrict__ dst,
                       int* __restrict__ cursor, int* __restrict__ colidx){
  int e = blockIdx.x*blockDim.x + threadIdx.x;
  if(e < NE){
    int pos = atomicAdd(&cursor[dst[e]], 1);
    colidx[pos] = src[e];
  }
}

__global__ void k_cvtx(const float* __restrict__ x, _Float16* __restrict__ act){
  int i = blockIdx.x*256 + threadIdx.x;
  if(i < NN*64) act[i] = (_Float16)x[i];
}

// identity BN coefficients for layer 1
__global__ void k_coef_id(float* __restrict__ cs, float* __restrict__ csh,
                          _Float16* __restrict__ cs16, _Float16* __restrict__ csh16){
  int c = threadIdx.x;
  cs[c] = 1.f; csh[c] = 0.f;
  cs16[c] = (_Float16)1.f; csh16[c] = (_Float16)0.f;
}

// BN coefficients from stats: v' = a*v + b with a=inv*gamma, b=beta-mean*a
__global__ void k_bn_coef(const float* __restrict__ colsum, const float* __restrict__ colss,
                          const float* __restrict__ gamma, const float* __restrict__ beta,
                          int dout, float* __restrict__ cs, float* __restrict__ csh,
                          _Float16* __restrict__ cs16, _Float16* __restrict__ csh16){
  int c = threadIdx.x;
  if(c >= dout) return;
  float mean = colsum[c] / (float)NN;
  float var  = colss[c] / (float)NN - mean*mean;
  float inv  = rsqrtf(fmaxf(var, 0.f) + EPSV);
  float a = inv * gamma[c];
  float b = beta[c] - mean * a;
  cs[c] = a; csh[c] = b;
  cs16[c] = (_Float16)a; csh16[c] = (_Float16)b;
}

// ---------------- aggregation: 8 cols/lane, 16 B loads, BN-affine commuted ----------------
// Reads RAW act (pre-BN, relu'd); applies per-column affine (a,b) only in the
// epilogue: mean'=a*mean+b ; min/max swap on a<0 ; std'=sqrt(a^2*var+eps).
// aggs[chunk][n*256 + {0,64,128,192} + cl] = mean|min|max|std

__global__ __launch_bounds__(256) void k_agg8(
    const _Float16* __restrict__ act, int d,
    const int* __restrict__ rowptr, const int* __restrict__ colidx,
    const float* __restrict__ cs, const float* __restrict__ csh,
    _Float16* __restrict__ aggs, size_t aggN)
{
  int wv = threadIdx.x >> 6, lane = threadIdx.x & 63;
  int lpn = d >> 3;                 // lanes per node: 8/16/32
  int npw = 64 / lpn;               // nodes per wave: 8/4/2
  int n = blockIdx.x*(npw*4) + wv*npw + (lane / lpn);
  int c = (lane % lpn) * 8;         // 8 adjacent feature cols
  if(n >= NN) return;
  int beg = rowptr[n], end = rowptr[n+1];
  const _Float16* hp = act + c;

  float s[8], q[8], mn[8], mx[8];
  #pragma unroll
  for(int j = 0; j < 8; j++){ s[j]=0.f; q[j]=0.f; mn[j]=INFINITY; mx[j]=-INFINITY; }

#define ACC8(v) { _Pragma("unroll") for(int j=0;j<8;j++){ float a=(float)(v)[j]; \
    s[j]+=a; q[j]+=a*a; mn[j]=fminf(mn[j],a); mx[j]=fmaxf(mx[j],a); } }

  int e = beg;
  for(; e+4 <= end; e+=4){
    int i0=colidx[e], i1=colidx[e+1], i2=colidx[e+2], i3=colidx[e+3];
    h8 v0 = *(const h8*)(hp + (size_t)i0*d);
    h8 v1 = *(const h8*)(hp + (size_t)i1*d);
    h8 v2 = *(const h8*)(hp + (size_t)i2*d);
    h8 v3 = *(const h8*)(hp + (size_t)i3*d);
    ACC8(v0) ACC8(v1) ACC8(v2) ACC8(v3)
  }
  for(; e < end; e++){
    h8 v = *(const h8*)(hp + (size_t)colidx[e]*d);
    ACC8(v)
  }
#undef ACC8

  float cnt = (end>beg) ? (float)(end-beg) : 1.f;
  h8 vm, vn, vx, vs;
  #pragma unroll
  for(int j = 0; j < 8; j++){
    float a = cs[c+j], b = csh[c+j];
    float mean_r = s[j]/cnt;
    float var_r  = fmaxf(q[j]/cnt - mean_r*mean_r, 0.f);
    float meanp = a*mean_r + b;
    float mnp = (a >= 0.f) ? a*mn[j]+b : a*mx[j]+b;
    float mxp = (a >= 0.f) ? a*mx[j]+b : a*mn[j]+b;
    float sdp = sqrtf(a*a*var_r + EPSV);
    if(end <= beg){ meanp = 0.f; mnp = 0.f; mxp = 0.f; sdp = sqrtf(EPSV); }
    vm[j] = (_Float16)meanp; vn[j] = (_Float16)mnp;
    vx[j] = (_Float16)mxp;   vs[j] = (_Float16)sdp;
  }

  _Float16* dst = aggs + (size_t)(c>>6)*aggN + (size_t)n*256 + (c & 63);
  *(h8*)(dst)       = vm;
  *(h8*)(dst + 64)  = vn;
  *(h8*)(dst + 128) = vx;
  *(h8*)(dst + 192) = vs;
}

// ---------------- fused W pre-pack (all layers/chunks, one kernel) ----------------
// Per chunk slab: Wp[kb=K/32][nt=o/16][lane=64][j=8]; row perm: k<64 -> j0+k ;
// [64,320)->(1+q)d+j0+r ; [320,576)->(5+q)d+j0+r ; [576,832)->(9+q)d+j0+r

struct PackJob { const float* W; _Float16* dst; int d, o, j0, start; };
struct PackArgs { PackJob job[9]; int total; };

__global__ void k_pack_all(PackArgs a){
  int idx = blockIdx.x*256 + threadIdx.x;
  if(idx >= a.total) return;
  int ji = 0;
  while(ji < 8 && idx >= a.job[ji+1].start) ji++;
  PackJob J = a.job[ji];
  int rel = idx - J.start;
  int j    = rel & 7;
  int lane = (rel >> 3) & 63;
  int rem  = rel >> 9;
  int ntiles = J.o >> 4;
  int kb = rem / ntiles;
  int nt = rem - kb*ntiles;
  int k = kb*32 + (lane>>4)*8 + j;
  int n = nt*16 + (lane&15);
  int srcrow;
  if(k < 64)       srcrow = J.j0 + k;
  else if(k < 320){ int t=k-64;  srcrow = (1+(t>>6))*J.d + J.j0 + (t&63); }
  else if(k < 576){ int t=k-320; srcrow = (5+(t>>6))*J.d + J.j0 + (t&63); }
  else            { int t=k-576; srcrow = (9+(t>>6))*J.d + J.j0 + (t&63); }
  J.dst[rel] = (_Float16)J.W[(size_t)srcrow*J.o + n];
}

// ---------------- fused MFMA layer GEMM (r9 geometry: 4 waves x 32 rows, 64 cols) ----------------
// x-phase A-frags read RAW act + apply BN affine (fp16 packed).
// Epilogue: +bias, ReLU, fp16 store (pre-BN activation of this layer).

__global__ __launch_bounds__(256) void k_mfma_fused(
    const _Float16* __restrict__ actIn, int d, int nch,
    const _Float16* __restrict__ aggs,          // [nch][NN][256], already affine'd
    const float* __restrict__ amp, const float* __restrict__ att,
    const _Float16* __restrict__ cs16, const _Float16* __restrict__ csh16,
    const _Float16* __restrict__ Wp, int o,     // [nch][832*o]
    const float* __restrict__ bias,
    _Float16* __restrict__ out)                 // [NN][o], relu'd pre-BN
{
  int tid  = threadIdx.x;
  int wv   = tid >> 6;
  int lane = tid & 63;
  int mi   = lane & 15;
  int q    = lane >> 4;
  int m0   = blockIdx.y * 128 + wv * 32;
  int c0   = blockIdx.x * 64;
  int ntiles = o >> 4;
  int nt0  = blockIdx.x * 4;

  int mrow[2];
  mrow[0] = min(m0 + mi,      NN-1);
  mrow[1] = min(m0 + 16 + mi, NN-1);
  _Float16 am16[2] = { (_Float16)amp[mrow[0]], (_Float16)amp[mrow[1]] };
  _Float16 at16[2] = { (_Float16)att[mrow[0]], (_Float16)att[mrow[1]] };
  const _Float16* hAb[2];
  const _Float16* agb[2];
  hAb[0] = actIn + (size_t)mrow[0]*d + q*8;
  hAb[1] = actIn + (size_t)mrow[1]*d + q*8;
  agb[0] = aggs + (size_t)mrow[0]*256 + q*8;
  agb[1] = aggs + (size_t)mrow[1]*256 + q*8;

  f4 acc[2][4] = {};
  const size_t aggN = (size_t)NN*256;

  for(int c = 0; c < nch; c++){
    const _Float16* Wpc = Wp + (size_t)c*832*o;
    auto bfrag = [&](int kb, int nn) -> h8 {
      return *(const h8*)(Wpc + (((size_t)kb*ntiles + nt0 + nn)*64 + lane)*8);
    };

    // ---- A fragments (prefetch): x-phase with BN affine, aggs raw ----
    h8 ax[2][2];
    h8 ag[8][2];
    #pragma unroll
    for(int kb = 0; kb < 2; kb++){
      h8 sc = *(const h8*)(cs16  + c*64 + kb*32 + q*8);
      h8 sh = *(const h8*)(csh16 + c*64 + kb*32 + q*8);
      #pragma unroll
      for(int t = 0; t < 2; t++){
        h8 a = *(const h8*)(hAb[t] + c*64 + kb*32);
        ax[kb][t] = a*sc + sh;
      }
    }
    #pragma unroll
    for(int idx = 0; idx < 8; idx++)
      #pragma unroll
      for(int t = 0; t < 2; t++)
        ag[idx][t] = *(const h8*)(agb[t] + (size_t)c*aggN + idx*32);

    // ---- phase X: kb = 0,1 ----
    #pragma unroll
    for(int kb = 0; kb < 2; kb++)
      #pragma unroll
      for(int t = 0; t < 2; t++)
        #pragma unroll
        for(int nn = 0; nn < 4; nn++)
          acc[t][nn] = __builtin_amdgcn_mfma_f32_16x16x32_f16(ax[kb][t], bfrag(kb,nn), acc[t][nn], 0,0,0);

    // ---- aggs phases: plain / amp-scaled / att-scaled ----
    #pragma unroll
    for(int idx = 0; idx < 8; idx++){
      #pragma unroll
      for(int t = 0; t < 2; t++){
        h8 apl = ag[idx][t];
        h8 aam = apl * am16[t];
        h8 aat = apl * at16[t];
        #pragma unroll
        for(int nn = 0; nn < 4; nn++){
          acc[t][nn] = __builtin_amdgcn_mfma_f32_16x16x32_f16(apl, bfrag(2+idx,  nn), acc[t][nn], 0,0,0);
          acc[t][nn] = __builtin_amdgcn_mfma_f32_16x16x32_f16(aam, bfrag(10+idx, nn), acc[t][nn], 0,0,0);
          acc[t][nn] = __builtin_amdgcn_mfma_f32_16x16x32_f16(aat, bfrag(18+idx, nn), acc[t][nn], 0,0,0);
        }
      }
    }
  }

  // ---- epilogue: +bias, ReLU, fp16 store. D col = lane&15, row = q*4+reg ----
  #pragma unroll
  for(int t = 0; t < 2; t++){
    #pragma unroll
    for(int nn = 0; nn < 4; nn++){
      int n = c0 + nn*16 + mi;
      float bv = bias[n];
      #pragma unroll
      for(int r = 0; r < 4; r++){
        int m = m0 + t*16 + q*4 + r;
        if(m < NN)
          out[(size_t)m*o + n] = (_Float16)fmaxf(bv + acc[t][nn][r], 0.f);
      }
    }
  }
}

// ---------------- BN stats (input already relu'd, fp16) ----------------

__global__ __launch_bounds__(256) void k_bn_stats(const _Float16* __restrict__ H, int dout,
                                                  float* __restrict__ colsum, float* __restrict__ colss){
  int tid = threadIdx.x;
  int gid = blockIdx.x*256 + tid;
  int stride = gridDim.x*256;
  int total = NN * dout;
  float s = 0.f, ss = 0.f;
  for(int i = gid; i < total; i += stride){
    float v = (float)H[i];
    s += v; ss += v*v;
  }
  __shared__ float shs[256], shss[256];
  shs[tid] = s; shss[tid] = ss;
  __syncthreads();
  if(tid < dout){
    float ts = 0.f, tss = 0.f;
    for(int i = tid; i < 256; i += dout){ ts += shs[i]; tss += shss[i]; }
    atomicAdd(&colsum[tid], ts);
    atomicAdd(&colss[tid], tss);
  }
}

// ---------------- classifier (applies final BN affine on load) ----------------

__global__ __launch_bounds__(256) void k_cls(const _Float16* __restrict__ h,
    const float* __restrict__ cs, const float* __restrict__ csh,
    const float* __restrict__ Wc, const float* __restrict__ bc,
    float* __restrict__ out){
  __shared__ float w[640];
  __shared__ float bb[16];
  __shared__ float sca[64], shb[64];
  int tid = threadIdx.x;
  for(int i = tid; i < 640; i += 256) w[i] = Wc[i];
  if(tid < 10) bb[tid] = bc[tid];
  if(tid < 64){ sca[tid] = cs[tid]; shb[tid] = csh[tid]; }
  __syncthreads();
  int idx = blockIdx.x*256 + tid;
  int n = idx >> 4;
  int c = idx & 15;
  if(n < NN && c < 10){
    float acc = bb[c];
    const _Float16* hp = h + (size_t)n*64;
    #pragma unroll
    for(int k = 0; k < 64; k++)
      acc += ((float)hp[k]*sca[k] + shb[k]) * w[k*10 + c];
    out[(size_t)n*10 + c] = acc;
  }
}

// ---------------- launch ----------------

extern "C" void kernel_launch(void* const* d_in, const int* in_sizes, int n_in,
                              void* d_out, int out_size, void* d_ws, size_t ws_size,
                              hipStream_t stream){
  const float* x = (const float*)d_in[0];
  const int* edge = (const int*)d_in[1];
  const int* esrc = edge;
  const int* edst = edge + NE;
  const float* W[4]  = {(const float*)d_in[2],  (const float*)d_in[6],
                        (const float*)d_in[10], (const float*)d_in[14]};
  const float* bb[4] = {(const float*)d_in[3],  (const float*)d_in[7],
                        (const float*)d_in[11], (const float*)d_in[15]};
  const float* gm[4] = {(const float*)d_in[4],  (const float*)d_in[8],
                        (const float*)d_in[12], (const float*)d_in[16]};
  const float* bt[4] = {(const float*)d_in[5],  (const float*)d_in[9],
                        (const float*)d_in[13], (const float*)d_in[17]};
  const float* Wc = (const float*)d_in[18];
  const float* bc = (const float*)d_in[19];
  (void)in_sizes; (void)n_in; (void)out_size; (void)ws_size;

  // workspace carve (~158 MB; proven-safe envelope)
  char* p = (char*)d_ws;
  auto alloc = [&](size_t bytes)->char*{
    char* r = p; p += (bytes + 255) & ~(size_t)255; return r;
  };
  _Float16* act0 = (_Float16*)alloc((size_t)NN*256*2);   // 25.6 MB
  _Float16* act1 = (_Float16*)alloc((size_t)NN*256*2);   // 25.6 MB
  _Float16* aggs = (_Float16*)alloc((size_t)4*NN*256*2); // 102.4 MB: [chunk][N][256]
  int*   deg    = (int*)  alloc((size_t)NN*4);
  float* logdeg = (float*)alloc((size_t)NN*4);
  float* amp    = (float*)alloc((size_t)NN*4);
  float* att    = (float*)alloc((size_t)NN*4);
  int*   rowptr = (int*)  alloc((size_t)(NN+1)*4);
  int*   cursor = (int*)  alloc((size_t)NN*4);
  int*   colidx = (int*)  alloc((size_t)NE*4);
  int*   bsum   = (int*)  alloc((size_t)(NB+1)*4);
  float* colsumL= (float*)alloc(4*256*4);   // per-layer BN partials
  float* colssL = (float*)alloc(4*256*4);
  float* dsum   = (float*)alloc(256);
  // BN coefficient double-buffers (fp32 + fp16)
  float*    csA  = (float*)   alloc(256*4);
  float*    cshA = (float*)   alloc(256*4);
  float*    csB  = (float*)   alloc(256*4);
  float*    cshB = (float*)   alloc(256*4);
  _Float16* cs16A  = (_Float16*)alloc(256*2);
  _Float16* csh16A = (_Float16*)alloc(256*2);
  _Float16* cs16B  = (_Float16*)alloc(256*2);
  _Float16* csh16B = (_Float16*)alloc(256*2);

  const int din[4]  = {64, 128, 256, 128};
  const int dto[4]  = {128, 256, 128, 64};
  const size_t aggN = (size_t)NN*256;      // halves per chunk slab
  _Float16* WpL[4];
  PackArgs pa; int pj = 0, poff = 0;
  for(int l = 0; l < 4; l++){
    int nch = din[l]/64;
    WpL[l] = (_Float16*)alloc((size_t)nch*832*dto[l]*2);
    for(int c = 0; c < nch; c++){
      pa.job[pj] = { W[l], WpL[l] + (size_t)c*832*dto[l], din[l], dto[l], c*64, poff };
      poff += 832*dto[l]; pj++;
    }
  }
  pa.total = poff;

  hipMemsetAsync(deg, 0, (size_t)NN*4, stream);
  hipMemsetAsync(dsum, 0, 4, stream);
  hipMemsetAsync(colsumL, 0, 4*256*4, stream);
  hipMemsetAsync(colssL,  0, 4*256*4, stream);

  k_pack_all<<<(pa.total+255)/256, 256, 0, stream>>>(pa);
  k_deg     <<<(NE+255)/256, 256, 0, stream>>>(edst, deg);
  k_logdeg  <<<(NN+255)/256, 256, 0, stream>>>(deg, logdeg, dsum);
  k_scalers <<<(NN+255)/256, 256, 0, stream>>>(logdeg, dsum, amp, att);
  k_scan1   <<<NB, 1024, 0, stream>>>(deg, rowptr, bsum);
  k_scan2   <<<1, 64, 0, stream>>>(bsum);
  k_scan3   <<<(NN+256)/256, 256, 0, stream>>>(rowptr, cursor, bsum);
  k_fill    <<<(NE+255)/256, 256, 0, stream>>>(esrc, edst, cursor, colidx);
  k_cvtx    <<<(NN*64+255)/256, 256, 0, stream>>>(x, act0);
  k_coef_id <<<1, 256, 0, stream>>>(csA, cshA, cs16A, csh16A);

  _Float16* actIn = act0;  _Float16* actOut = act1;
  float *csI = csA, *cshI = cshA, *csO = csB, *cshO = cshB;
  _Float16 *cs16I = cs16A, *csh16I = csh16A, *cs16O = cs16B, *csh16O = csh16B;

  for(int l = 0; l < 4; l++){
    int d = din[l], o = dto[l];
    int nch = d / 64;
    int npb = (64 / (d >> 3)) * 4;          // nodes per block in k_agg8
    k_agg8<<<(NN+npb-1)/npb, 256, 0, stream>>>(actIn, d, rowptr, colidx,
                                               csI, cshI, aggs, aggN);
    dim3 g(o/64, (NN+127)/128);
    k_mfma_fused<<<g, 256, 0, stream>>>(actIn, d, nch, aggs, amp, att,
                                        cs16I, csh16I, WpL[l], o, bb[l], actOut);
    k_bn_stats<<<256, 256, 0, stream>>>(actOut, o, colsumL + l*256, colssL + l*256);
    k_bn_coef<<<1, 256, 0, stream>>>(colsumL + l*256, colssL + l*256, gm[l], bt[l], o,
                                     csO, cshO, cs16O, csh16O);
    // swap activation and coefficient buffers
    _Float16* ta = actIn; actIn = actOut; actOut = ta;
    float* tf;
    tf = csI;  csI = csO;  csO = tf;
    tf = cshI; cshI = cshO; cshO = tf;
    _Float16* th;
    th = cs16I;  cs16I = cs16O;  cs16O = th;
    th = csh16I; csh16I = csh16O; csh16O = th;
  }
  k_cls<<<(NN*16+255)/256, 256, 0, stream>>>(actIn, csI, cshI, Wc, bc, (float*)d_out);
}

// Round 14
// 743.564 us; speedup vs baseline: 1.1854x; 1.0818x over previous
//
#include <hip/hip_runtime.h>
#include <hip/hip_bf16.h>

#define NN 50000
#define NE 800000
#define EPSV 1e-5f
#define NB 49   // scan blocks: ceil(NN/1024)

typedef _Float16 h8 __attribute__((ext_vector_type(8)));
typedef float    f4 __attribute__((ext_vector_type(4)));

// ---------------- graph preprocessing ----------------

__global__ void k_deg(const int* __restrict__ dst, int* __restrict__ deg){
  int e = blockIdx.x*blockDim.x + threadIdx.x;
  if(e < NE) atomicAdd(&deg[dst[e]], 1);
}

__global__ void k_logdeg(const int* __restrict__ deg, float* __restrict__ logdeg,
                         float* __restrict__ dsum){
  int i = blockIdx.x*blockDim.x + threadIdx.x;
  float v = 0.f;
  if(i < NN){ v = log1pf((float)deg[i]); logdeg[i] = v; }
  __shared__ float sh[256];
  sh[threadIdx.x] = v; __syncthreads();
  for(int off=128; off>0; off>>=1){
    if(threadIdx.x < off) sh[threadIdx.x] += sh[threadIdx.x+off];
    __syncthreads();
  }
  if(threadIdx.x == 0) atomicAdd(dsum, sh[0]);
}

__global__ void k_scalers(const float* __restrict__ logdeg, const float* __restrict__ dsum,
                          float* __restrict__ amp, float* __restrict__ att){
  int i = blockIdx.x*blockDim.x + threadIdx.x;
  if(i >= NN) return;
  float delta = dsum[0] / (float)NN;
  float ld = logdeg[i];
  amp[i] = ld / delta;
  att[i] = (ld > 0.f) ? (delta / fmaxf(ld, 1e-6f)) : 1.f;
}

// 3-phase parallel exclusive scan of deg -> rowptr (+cursor copy)
__global__ void k_scan1(const int* __restrict__ deg, int* __restrict__ rowptr,
                        int* __restrict__ bsum){
  __shared__ int buf[1024];
  int tid = threadIdx.x;
  int i = blockIdx.x*1024 + tid;
  int v = (i < NN) ? deg[i] : 0;
  buf[tid] = v; __syncthreads();
  for(int off=1; off<1024; off<<=1){
    int t = (tid >= off) ? buf[tid-off] : 0;
    __syncthreads();
    buf[tid] += t;
    __syncthreads();
  }
  if(i < NN) rowptr[i] = buf[tid] - v;
  if(tid == 1023) bsum[blockIdx.x] = buf[1023];
}

__global__ void k_scan2(int* __restrict__ bsum){
  if(threadIdx.x == 0){
    int s = 0;
    for(int b = 0; b < NB; b++){ int t = bsum[b]; bsum[b] = s; s += t; }
    bsum[NB] = s;
  }
}

__global__ void k_scan3(int* __restrict__ rowptr, int* __restrict__ cursor,
                        const int* __restrict__ bsum){
  int i = blockIdx.x*256 + threadIdx.x;
  if(i < NN){
    int v = rowptr[i] + bsum[i >> 10];
    rowptr[i] = v; cursor[i] = v;
  }
  if(i == NN) rowptr[NN] = bsum[NB];
}

__global__ void k_fill(const int* __restrict__ src, const int* __restrict__ dst,
                       int* __restrict__ cursor, int* __restrict__ colidx){
  int e = blockIdx.x*blockDim.x + threadIdx.x;
  if(e < NE){
    int pos = atomicAdd(&cursor[dst[e]], 1);
    colidx[pos] = src[e];
  }
}

__global__ void k_cvtx(const float* __restrict__ x, _Float16* __restrict__ act){
  int i = blockIdx.x*256 + threadIdx.x;
  if(i < NN*64) act[i] = (_Float16)x[i];
}

// identity BN coefficients for layer 1
__global__ void k_coef_id(float* __restrict__ cs, float* __restrict__ csh,
                          _Float16* __restrict__ cs16, _Float16* __restrict__ csh16){
  int c = threadIdx.x;
  cs[c] = 1.f; csh[c] = 0.f;
  cs16[c] = (_Float16)1.f; csh16[c] = (_Float16)0.f;
}

// BN coefficients from stats: v' = a*v + b with a=inv*gamma, b=beta-mean*a
__global__ void k_bn_coef(const float* __restrict__ colsum, const float* __restrict__ colss,
                          const float* __restrict__ gamma, const float* __restrict__ beta,
                          int dout, float* __restrict__ cs, float* __restrict__ csh,
                          _Float16* __restrict__ cs16, _Float16* __restrict__ csh16){
  int c = threadIdx.x;
  if(c >= dout) return;
  float mean = colsum[c] / (float)NN;
  float var  = colss[c] / (float)NN - mean*mean;
  float inv  = rsqrtf(fmaxf(var, 0.f) + EPSV);
  float a = inv * gamma[c];
  float b = beta[c] - mean * a;
  cs[c] = a; csh[c] = b;
  cs16[c] = (_Float16)a; csh16[c] = (_Float16)b;
}

// ---------------- aggregation: 8 cols/lane, 16 B loads, 8-edge unroll ----------------
// Reads RAW act (pre-BN, relu'd); applies per-column affine (a,b) in the
// epilogue: mean'=a*mean+b ; min/max swap on a<0 ; std'=sqrt(a^2*var+eps).
// aggs[chunk][n*256 + {0,64,128,192} + cl] = mean|min|max|std

__global__ __launch_bounds__(256) void k_agg8(
    const _Float16* __restrict__ act, int d,
    const int* __restrict__ rowptr, const int* __restrict__ colidx,
    const float* __restrict__ cs, const float* __restrict__ csh,
    _Float16* __restrict__ aggs, size_t aggN)
{
  int wv = threadIdx.x >> 6, lane = threadIdx.x & 63;
  int lpn = d >> 3;                 // lanes per node: 8/16/32
  int npw = 64 / lpn;               // nodes per wave: 8/4/2
  int n = blockIdx.x*(npw*4) + wv*npw + (lane / lpn);
  int c = (lane % lpn) * 8;         // 8 adjacent feature cols
  if(n >= NN) return;
  int beg = rowptr[n], end = rowptr[n+1];
  const _Float16* hp = act + c;

  float s[8], q[8], mn[8], mx[8];
  #pragma unroll
  for(int j = 0; j < 8; j++){ s[j]=0.f; q[j]=0.f; mn[j]=INFINITY; mx[j]=-INFINITY; }

#define ACC8(v) { _Pragma("unroll") for(int j=0;j<8;j++){ float a=(float)(v)[j]; \
    s[j]+=a; q[j]+=a*a; mn[j]=fminf(mn[j],a); mx[j]=fmaxf(mx[j],a); } }

  int e = beg;
  for(; e+8 <= end; e+=8){
    int i0=colidx[e],   i1=colidx[e+1], i2=colidx[e+2], i3=colidx[e+3];
    int i4=colidx[e+4], i5=colidx[e+5], i6=colidx[e+6], i7=colidx[e+7];
    h8 v0 = *(const h8*)(hp + (size_t)i0*d);
    h8 v1 = *(const h8*)(hp + (size_t)i1*d);
    h8 v2 = *(const h8*)(hp + (size_t)i2*d);
    h8 v3 = *(const h8*)(hp + (size_t)i3*d);
    h8 v4 = *(const h8*)(hp + (size_t)i4*d);
    h8 v5 = *(const h8*)(hp + (size_t)i5*d);
    h8 v6 = *(const h8*)(hp + (size_t)i6*d);
    h8 v7 = *(const h8*)(hp + (size_t)i7*d);
    ACC8(v0) ACC8(v1) ACC8(v2) ACC8(v3) ACC8(v4) ACC8(v5) ACC8(v6) ACC8(v7)
  }
  for(; e+4 <= end; e+=4){
    int i0=colidx[e], i1=colidx[e+1], i2=colidx[e+2], i3=colidx[e+3];
    h8 v0 = *(const h8*)(hp + (size_t)i0*d);
    h8 v1 = *(const h8*)(hp + (size_t)i1*d);
    h8 v2 = *(const h8*)(hp + (size_t)i2*d);
    h8 v3 = *(const h8*)(hp + (size_t)i3*d);
    ACC8(v0) ACC8(v1) ACC8(v2) ACC8(v3)
  }
  for(; e < end; e++){
    h8 v = *(const h8*)(hp + (size_t)colidx[e]*d);
    ACC8(v)
  }
#undef ACC8

  float cnt = (end>beg) ? (float)(end-beg) : 1.f;
  h8 vm, vn, vx, vs;
  #pragma unroll
  for(int j = 0; j < 8; j++){
    float a = cs[c+j], b = csh[c+j];
    float mean_r = s[j]/cnt;
    float var_r  = fmaxf(q[j]/cnt - mean_r*mean_r, 0.f);
    float meanp = a*mean_r + b;
    float mnp = (a >= 0.f) ? a*mn[j]+b : a*mx[j]+b;
    float mxp = (a >= 0.f) ? a*mx[j]+b : a*mn[j]+b;
    float sdp = sqrtf(a*a*var_r + EPSV);
    if(end <= beg){ meanp = 0.f; mnp = 0.f; mxp = 0.f; sdp = sqrtf(EPSV); }
    vm[j] = (_Float16)meanp; vn[j] = (_Float16)mnp;
    vx[j] = (_Float16)mxp;   vs[j] = (_Float16)sdp;
  }

  _Float16* dst = aggs + (size_t)(c>>6)*aggN + (size_t)n*256 + (c & 63);
  *(h8*)(dst)       = vm;
  *(h8*)(dst + 64)  = vn;
  *(h8*)(dst + 128) = vx;
  *(h8*)(dst + 192) = vs;
}

// ---------------- fused W pre-pack (all layers/chunks, one kernel) ----------------
// Per chunk slab: Wp[kb=K/32][nt=o/16][lane=64][j=8]; row perm: k<64 -> j0+k ;
// [64,320)->(1+q)d+j0+r ; [320,576)->(5+q)d+j0+r ; [576,832)->(9+q)d+j0+r

struct PackJob { const float* W; _Float16* dst; int d, o, j0, start; };
struct PackArgs { PackJob job[9]; int total; };

__global__ void k_pack_all(PackArgs a){
  int idx = blockIdx.x*256 + threadIdx.x;
  if(idx >= a.total) return;
  int ji = 0;
  while(ji < 8 && idx >= a.job[ji+1].start) ji++;
  PackJob J = a.job[ji];
  int rel = idx - J.start;
  int j    = rel & 7;
  int lane = (rel >> 3) & 63;
  int rem  = rel >> 9;
  int ntiles = J.o >> 4;
  int kb = rem / ntiles;
  int nt = rem - kb*ntiles;
  int k = kb*32 + (lane>>4)*8 + j;
  int n = nt*16 + (lane&15);
  int srcrow;
  if(k < 64)       srcrow = J.j0 + k;
  else if(k < 320){ int t=k-64;  srcrow = (1+(t>>6))*J.d + J.j0 + (t&63); }
  else if(k < 576){ int t=k-320; srcrow = (5+(t>>6))*J.d + J.j0 + (t&63); }
  else            { int t=k-576; srcrow = (9+(t>>6))*J.d + J.j0 + (t&63); }
  J.dst[rel] = (_Float16)J.W[(size_t)srcrow*J.o + n];
}

// ---------------- fused MFMA layer GEMM + fused BN-stats epilogue ----------------
// r9/r13 geometry: 4 waves x 32 rows = 128 rows, 64 cols. x-phase A-frags get
// BN affine; epilogue computes +bias, ReLU, fp16 store AND per-column
// sum/sumsq (LDS reduce + global atomics) so k_bn_stats disappears.

__global__ __launch_bounds__(256) void k_mfma_fused(
    const _Float16* __restrict__ actIn, int d, int nch,
    const _Float16* __restrict__ aggs,          // [nch][NN][256], already affine'd
    const float* __restrict__ amp, const float* __restrict__ att,
    const _Float16* __restrict__ cs16, const _Float16* __restrict__ csh16,
    const _Float16* __restrict__ Wp, int o,     // [nch][832*o]
    const float* __restrict__ bias,
    _Float16* __restrict__ out,                 // [NN][o], relu'd pre-BN
    float* __restrict__ colsum, float* __restrict__ colss)
{
  __shared__ float redS[64], redQ[64];
  int tid  = threadIdx.x;
  int wv   = tid >> 6;
  int lane = tid & 63;
  int mi   = lane & 15;
  int q    = lane >> 4;
  int m0   = blockIdx.y * 128 + wv * 32;
  int c0   = blockIdx.x * 64;
  int ntiles = o >> 4;
  int nt0  = blockIdx.x * 4;

  if(tid < 64){ redS[tid] = 0.f; redQ[tid] = 0.f; }

  int mrow[2];
  mrow[0] = min(m0 + mi,      NN-1);
  mrow[1] = min(m0 + 16 + mi, NN-1);
  _Float16 am16[2] = { (_Float16)amp[mrow[0]], (_Float16)amp[mrow[1]] };
  _Float16 at16[2] = { (_Float16)att[mrow[0]], (_Float16)att[mrow[1]] };
  const _Float16* hAb[2];
  const _Float16* agb[2];
  hAb[0] = actIn + (size_t)mrow[0]*d + q*8;
  hAb[1] = actIn + (size_t)mrow[1]*d + q*8;
  agb[0] = aggs + (size_t)mrow[0]*256 + q*8;
  agb[1] = aggs + (size_t)mrow[1]*256 + q*8;

  f4 acc[2][4] = {};
  const size_t aggN = (size_t)NN*256;

  for(int c = 0; c < nch; c++){
    const _Float16* Wpc = Wp + (size_t)c*832*o;
    auto bfrag = [&](int kb, int nn) -> h8 {
      return *(const h8*)(Wpc + (((size_t)kb*ntiles + nt0 + nn)*64 + lane)*8);
    };

    // ---- A fragments (prefetch): x-phase with BN affine, aggs raw ----
    h8 ax[2][2];
    h8 ag[8][2];
    #pragma unroll
    for(int kb = 0; kb < 2; kb++){
      h8 sc = *(const h8*)(cs16  + c*64 + kb*32 + q*8);
      h8 sh = *(const h8*)(csh16 + c*64 + kb*32 + q*8);
      #pragma unroll
      for(int t = 0; t < 2; t++){
        h8 a = *(const h8*)(hAb[t] + c*64 + kb*32);
        ax[kb][t] = a*sc + sh;
      }
    }
    #pragma unroll
    for(int idx = 0; idx < 8; idx++)
      #pragma unroll
      for(int t = 0; t < 2; t++)
        ag[idx][t] = *(const h8*)(agb[t] + (size_t)c*aggN + idx*32);

    // ---- phase X: kb = 0,1 ----
    #pragma unroll
    for(int kb = 0; kb < 2; kb++)
      #pragma unroll
      for(int t = 0; t < 2; t++)
        #pragma unroll
        for(int nn = 0; nn < 4; nn++)
          acc[t][nn] = __builtin_amdgcn_mfma_f32_16x16x32_f16(ax[kb][t], bfrag(kb,nn), acc[t][nn], 0,0,0);

    // ---- aggs phases: plain / amp-scaled / att-scaled ----
    #pragma unroll
    for(int idx = 0; idx < 8; idx++){
      #pragma unroll
      for(int t = 0; t < 2; t++){
        h8 apl = ag[idx][t];
        h8 aam = apl * am16[t];
        h8 aat = apl * at16[t];
        #pragma unroll
        for(int nn = 0; nn < 4; nn++){
          acc[t][nn] = __builtin_amdgcn_mfma_f32_16x16x32_f16(apl, bfrag(2+idx,  nn), acc[t][nn], 0,0,0);
          acc[t][nn] = __builtin_amdgcn_mfma_f32_16x16x32_f16(aam, bfrag(10+idx, nn), acc[t][nn], 0,0,0);
          acc[t][nn] = __builtin_amdgcn_mfma_f32_16x16x32_f16(aat, bfrag(18+idx, nn), acc[t][nn], 0,0,0);
        }
      }
    }
  }

  __syncthreads();   // redS/redQ zero-init visible

  // ---- epilogue: +bias, ReLU, fp16 store + per-column stats ----
  #pragma unroll
  for(int t = 0; t < 2; t++){
    #pragma unroll
    for(int nn = 0; nn < 4; nn++){
      int n = c0 + nn*16 + mi;
      float bv = bias[n];
      float ps = 0.f, pq = 0.f;
      #pragma unroll
      for(int r = 0; r < 4; r++){
        int m = m0 + t*16 + q*4 + r;
        if(m < NN){
          float v = fmaxf(bv + acc[t][nn][r], 0.f);
          out[(size_t)m*o + n] = (_Float16)v;
          ps += v; pq += v*v;
        }
      }
      atomicAdd(&redS[nn*16 + mi], ps);
      atomicAdd(&redQ[nn*16 + mi], pq);
    }
  }
  __syncthreads();
  if(tid < 64){
    atomicAdd(&colsum[c0 + tid], redS[tid]);
    atomicAdd(&colss[c0 + tid],  redQ[tid]);
  }
}

// ---------------- classifier (applies final BN affine on load) ----------------

__global__ __launch_bounds__(256) void k_cls(const _Float16* __restrict__ h,
    const float* __restrict__ cs, const float* __restrict__ csh,
    const float* __restrict__ Wc, const float* __restrict__ bc,
    float* __restrict__ out){
  __shared__ float w[640];
  __shared__ float bb[16];
  __shared__ float sca[64], shb[64];
  int tid = threadIdx.x;
  for(int i = tid; i < 640; i += 256) w[i] = Wc[i];
  if(tid < 10) bb[tid] = bc[tid];
  if(tid < 64){ sca[tid] = cs[tid]; shb[tid] = csh[tid]; }
  __syncthreads();
  int idx = blockIdx.x*256 + tid;
  int n = idx >> 4;
  int c = idx & 15;
  if(n < NN && c < 10){
    float acc = bb[c];
    const _Float16* hp = h + (size_t)n*64;
    #pragma unroll
    for(int k = 0; k < 64; k++)
      acc += ((float)hp[k]*sca[k] + shb[k]) * w[k*10 + c];
    out[(size_t)n*10 + c] = acc;
  }
}

// ---------------- launch ----------------

extern "C" void kernel_launch(void* const* d_in, const int* in_sizes, int n_in,
                              void* d_out, int out_size, void* d_ws, size_t ws_size,
                              hipStream_t stream){
  const float* x = (const float*)d_in[0];
  const int* edge = (const int*)d_in[1];
  const int* esrc = edge;
  const int* edst = edge + NE;
  const float* W[4]  = {(const float*)d_in[2],  (const float*)d_in[6],
                        (const float*)d_in[10], (const float*)d_in[14]};
  const float* bb[4] = {(const float*)d_in[3],  (const float*)d_in[7],
                        (const float*)d_in[11], (const float*)d_in[15]};
  const float* gm[4] = {(const float*)d_in[4],  (const float*)d_in[8],
                        (const float*)d_in[12], (const float*)d_in[16]};
  const float* bt[4] = {(const float*)d_in[5],  (const float*)d_in[9],
                        (const float*)d_in[13], (const float*)d_in[17]};
  const float* Wc = (const float*)d_in[18];
  const float* bc = (const float*)d_in[19];
  (void)in_sizes; (void)n_in; (void)out_size; (void)ws_size;

  // workspace carve (~158 MB; proven-safe envelope)
  char* p = (char*)d_ws;
  auto alloc = [&](size_t bytes)->char*{
    char* r = p; p += (bytes + 255) & ~(size_t)255; return r;
  };
  _Float16* act0 = (_Float16*)alloc((size_t)NN*256*2);   // 25.6 MB
  _Float16* act1 = (_Float16*)alloc((size_t)NN*256*2);   // 25.6 MB
  _Float16* aggs = (_Float16*)alloc((size_t)4*NN*256*2); // 102.4 MB: [chunk][N][256]
  int*   deg    = (int*)  alloc((size_t)NN*4);
  float* logdeg = (float*)alloc((size_t)NN*4);
  float* amp    = (float*)alloc((size_t)NN*4);
  float* att    = (float*)alloc((size_t)NN*4);
  int*   rowptr = (int*)  alloc((size_t)(NN+1)*4);
  int*   cursor = (int*)  alloc((size_t)NN*4);
  int*   colidx = (int*)  alloc((size_t)NE*4);
  int*   bsum   = (int*)  alloc((size_t)(NB+1)*4);
  float* colsumL= (float*)alloc(4*256*4);   // per-layer BN partials
  float* colssL = (float*)alloc(4*256*4);
  float* dsum   = (float*)alloc(256);
  // BN coefficient double-buffers (fp32 + fp16)
  float*    csA  = (float*)   alloc(256*4);
  float*    cshA = (float*)   alloc(256*4);
  float*    csB  = (float*)   alloc(256*4);
  float*    cshB = (float*)   alloc(256*4);
  _Float16* cs16A  = (_Float16*)alloc(256*2);
  _Float16* csh16A = (_Float16*)alloc(256*2);
  _Float16* cs16B  = (_Float16*)alloc(256*2);
  _Float16* csh16B = (_Float16*)alloc(256*2);

  const int din[4]  = {64, 128, 256, 128};
  const int dto[4]  = {128, 256, 128, 64};
  const size_t aggN = (size_t)NN*256;      // halves per chunk slab
  _Float16* WpL[4];
  PackArgs pa; int pj = 0, poff = 0;
  for(int l = 0; l < 4; l++){
    int nch = din[l]/64;
    WpL[l] = (_Float16*)alloc((size_t)nch*832*dto[l]*2);
    for(int c = 0; c < nch; c++){
      pa.job[pj] = { W[l], WpL[l] + (size_t)c*832*dto[l], din[l], dto[l], c*64, poff };
      poff += 832*dto[l]; pj++;
    }
  }
  pa.total = poff;

  hipMemsetAsync(deg, 0, (size_t)NN*4, stream);
  hipMemsetAsync(dsum, 0, 4, stream);
  hipMemsetAsync(colsumL, 0, 4*256*4, stream);
  hipMemsetAsync(colssL,  0, 4*256*4, stream);

  k_pack_all<<<(pa.total+255)/256, 256, 0, stream>>>(pa);
  k_deg     <<<(NE+255)/256, 256, 0, stream>>>(edst, deg);
  k_logdeg  <<<(NN+255)/256, 256, 0, stream>>>(deg, logdeg, dsum);
  k_scalers <<<(NN+255)/256, 256, 0, stream>>>(logdeg, dsum, amp, att);
  k_scan1   <<<NB, 1024, 0, stream>>>(deg, rowptr, bsum);
  k_scan2   <<<1, 64, 0, stream>>>(bsum);
  k_scan3   <<<(NN+256)/256, 256, 0, stream>>>(rowptr, cursor, bsum);
  k_fill    <<<(NE+255)/256, 256, 0, stream>>>(esrc, edst, cursor, colidx);
  k_cvtx    <<<(NN*64+255)/256, 256, 0, stream>>>(x, act0);
  k_coef_id <<<1, 256, 0, stream>>>(csA, cshA, cs16A, csh16A);

  _Float16* actIn = act0;  _Float16* actOut = act1;
  float *csI = csA, *cshI = cshA, *csO = csB, *cshO = cshB;
  _Float16 *cs16I = cs16A, *csh16I = csh16A, *cs16O = cs16B, *csh16O = csh16B;

  for(int l = 0; l < 4; l++){
    int d = din[l], o = dto[l];
    int nch = d / 64;
    int npb = (64 / (d >> 3)) * 4;          // nodes per block in k_agg8
    k_agg8<<<(NN+npb-1)/npb, 256, 0, stream>>>(actIn, d, rowptr, colidx,
                                               csI, cshI, aggs, aggN);
    dim3 g(o/64, (NN+127)/128);
    k_mfma_fused<<<g, 256, 0, stream>>>(actIn, d, nch, aggs, amp, att,
                                        cs16I, csh16I, WpL[l], o, bb[l], actOut,
                                        colsumL + l*256, colssL + l*256);
    k_bn_coef<<<1, 256, 0, stream>>>(colsumL + l*256, colssL + l*256, gm[l], bt[l], o,
                                     csO, cshO, cs16O, csh16O);
    // swap activation and coefficient buffers
    _Float16* ta = actIn; actIn = actOut; actOut = ta;
    float* tf;
    tf = csI;  csI = csO;  csO = tf;
    tf = cshI; cshI = cshO; cshO = tf;
    _Float16* th;
    th = cs16I;  cs16I = cs16O;  cs16O = th;
    th = csh16I; csh16I = csh16O; csh16O = th;
  }
  k_cls<<<(NN*16+255)/256, 256, 0, stream>>>(actIn, csI, cshI, Wc, bc, (float*)d_out);
}

// Round 15
// 704.377 us; speedup vs baseline: 1.2513x; 1.0556x over previous
//
#include <hip/hip_runtime.h>
#include <hip/hip_bf16.h>

#define NN 50000
#define NE 800000
#define EPSV 1e-5f
#define NB 49   // scan blocks: ceil(NN/1024)

typedef _Float16 h8 __attribute__((ext_vector_type(8)));
typedef float    f4 __attribute__((ext_vector_type(4)));

// ---------------- graph preprocessing ----------------

__global__ void k_deg(const int* __restrict__ dst, int* __restrict__ deg){
  int e = blockIdx.x*blockDim.x + threadIdx.x;
  if(e < NE) atomicAdd(&deg[dst[e]], 1);
}

__global__ void k_logdeg(const int* __restrict__ deg, float* __restrict__ logdeg,
                         float* __restrict__ dsum){
  int i = blockIdx.x*blockDim.x + threadIdx.x;
  float v = 0.f;
  if(i < NN){ v = log1pf((float)deg[i]); logdeg[i] = v; }
  __shared__ float sh[256];
  sh[threadIdx.x] = v; __syncthreads();
  for(int off=128; off>0; off>>=1){
    if(threadIdx.x < off) sh[threadIdx.x] += sh[threadIdx.x+off];
    __syncthreads();
  }
  if(threadIdx.x == 0) atomicAdd(dsum, sh[0]);
}

__global__ void k_scalers(const float* __restrict__ logdeg, const float* __restrict__ dsum,
                          float* __restrict__ amp, float* __restrict__ att){
  int i = blockIdx.x*blockDim.x + threadIdx.x;
  if(i >= NN) return;
  float delta = dsum[0] / (float)NN;
  float ld = logdeg[i];
  amp[i] = ld / delta;
  att[i] = (ld > 0.f) ? (delta / fmaxf(ld, 1e-6f)) : 1.f;
}

// 3-phase parallel exclusive scan of deg -> rowptr (+cursor copy)
__global__ void k_scan1(const int* __restrict__ deg, int* __restrict__ rowptr,
                        int* __restrict__ bsum){
  __shared__ int buf[1024];
  int tid = threadIdx.x;
  int i = blockIdx.x*1024 + tid;
  int v = (i < NN) ? deg[i] : 0;
  buf[tid] = v; __syncthreads();
  for(int off=1; off<1024; off<<=1){
    int t = (tid >= off) ? buf[tid-off] : 0;
    __syncthreads();
    buf[tid] += t;
    __syncthreads();
  }
  if(i < NN) rowptr[i] = buf[tid] - v;
  if(tid == 1023) bsum[blockIdx.x] = buf[1023];
}

__global__ void k_scan2(int* __restrict__ bsum){
  if(threadIdx.x == 0){
    int s = 0;
    for(int b = 0; b < NB; b++){ int t = bsum[b]; bsum[b] = s; s += t; }
    bsum[NB] = s;
  }
}

__global__ void k_scan3(int* __restrict__ rowptr, int* __restrict__ cursor,
                        const int* __restrict__ bsum){
  int i = blockIdx.x*256 + threadIdx.x;
  if(i < NN){
    int v = rowptr[i] + bsum[i >> 10];
    rowptr[i] = v; cursor[i] = v;
  }
  if(i == NN) rowptr[NN] = bsum[NB];
}

__global__ void k_fill(const int* __restrict__ src, const int* __restrict__ dst,
                       int* __restrict__ cursor, int* __restrict__ colidx){
  int e = blockIdx.x*blockDim.x + threadIdx.x;
  if(e < NE){
    int pos = atomicAdd(&cursor[dst[e]], 1);
    colidx[pos] = src[e];
  }
}

__global__ void k_cvtx(const float* __restrict__ x, _Float16* __restrict__ act){
  int i = blockIdx.x*256 + threadIdx.x;
  if(i < NN*64) act[i] = (_Float16)x[i];
}

// identity BN coefficients for layer 1
__global__ void k_coef_id(float* __restrict__ cs, float* __restrict__ csh,
                          _Float16* __restrict__ cs16, _Float16* __restrict__ csh16){
  int c = threadIdx.x;
  cs[c] = 1.f; csh[c] = 0.f;
  cs16[c] = (_Float16)1.f; csh16[c] = (_Float16)0.f;
}

// BN coefficients from stats: v' = a*v + b with a=inv*gamma, b=beta-mean*a
__global__ void k_bn_coef(const float* __restrict__ colsum, const float* __restrict__ colss,
                          const float* __restrict__ gamma, const float* __restrict__ beta,
                          int dout, float* __restrict__ cs, float* __restrict__ csh,
                          _Float16* __restrict__ cs16, _Float16* __restrict__ csh16){
  int c = threadIdx.x;
  if(c >= dout) return;
  float mean = colsum[c] / (float)NN;
  float var  = colss[c] / (float)NN - mean*mean;
  float inv  = rsqrtf(fmaxf(var, 0.f) + EPSV);
  float a = inv * gamma[c];
  float b = beta[c] - mean * a;
  cs[c] = a; csh[c] = b;
  cs16[c] = (_Float16)a; csh16[c] = (_Float16)b;
}

// ---------------- aggregation: 8 cols/lane, 16 B loads, 8-edge unroll ----------------
// Reads RAW act (pre-BN, relu'd); applies per-column affine (a,b) in the
// epilogue: mean'=a*mean+b ; min/max swap on a<0 ; std'=sqrt(a^2*var+eps).
// aggs[chunk][n*256 + {0,64,128,192} + cl] = mean|min|max|std

__global__ __launch_bounds__(256) void k_agg8(
    const _Float16* __restrict__ act, int d,
    const int* __restrict__ rowptr, const int* __restrict__ colidx,
    const float* __restrict__ cs, const float* __restrict__ csh,
    _Float16* __restrict__ aggs, size_t aggN)
{
  int wv = threadIdx.x >> 6, lane = threadIdx.x & 63;
  int lpn = d >> 3;                 // lanes per node: 8/16/32
  int npw = 64 / lpn;               // nodes per wave: 8/4/2
  int n = blockIdx.x*(npw*4) + wv*npw + (lane / lpn);
  int c = (lane % lpn) * 8;         // 8 adjacent feature cols
  if(n >= NN) return;
  int beg = rowptr[n], end = rowptr[n+1];
  const _Float16* hp = act + c;

  float s[8], q[8], mn[8], mx[8];
  #pragma unroll
  for(int j = 0; j < 8; j++){ s[j]=0.f; q[j]=0.f; mn[j]=INFINITY; mx[j]=-INFINITY; }

#define ACC8(v) { _Pragma("unroll") for(int j=0;j<8;j++){ float a=(float)(v)[j]; \
    s[j]+=a; q[j]+=a*a; mn[j]=fminf(mn[j],a); mx[j]=fmaxf(mx[j],a); } }

  int e = beg;
  for(; e+8 <= end; e+=8){
    int i0=colidx[e],   i1=colidx[e+1], i2=colidx[e+2], i3=colidx[e+3];
    int i4=colidx[e+4], i5=colidx[e+5], i6=colidx[e+6], i7=colidx[e+7];
    h8 v0 = *(const h8*)(hp + (size_t)i0*d);
    h8 v1 = *(const h8*)(hp + (size_t)i1*d);
    h8 v2 = *(const h8*)(hp + (size_t)i2*d);
    h8 v3 = *(const h8*)(hp + (size_t)i3*d);
    h8 v4 = *(const h8*)(hp + (size_t)i4*d);
    h8 v5 = *(const h8*)(hp + (size_t)i5*d);
    h8 v6 = *(const h8*)(hp + (size_t)i6*d);
    h8 v7 = *(const h8*)(hp + (size_t)i7*d);
    ACC8(v0) ACC8(v1) ACC8(v2) ACC8(v3) ACC8(v4) ACC8(v5) ACC8(v6) ACC8(v7)
  }
  for(; e+4 <= end; e+=4){
    int i0=colidx[e], i1=colidx[e+1], i2=colidx[e+2], i3=colidx[e+3];
    h8 v0 = *(const h8*)(hp + (size_t)i0*d);
    h8 v1 = *(const h8*)(hp + (size_t)i1*d);
    h8 v2 = *(const h8*)(hp + (size_t)i2*d);
    h8 v3 = *(const h8*)(hp + (size_t)i3*d);
    ACC8(v0) ACC8(v1) ACC8(v2) ACC8(v3)
  }
  for(; e < end; e++){
    h8 v = *(const h8*)(hp + (size_t)colidx[e]*d);
    ACC8(v)
  }
#undef ACC8

  float cnt = (end>beg) ? (float)(end-beg) : 1.f;
  h8 vm, vn, vx, vs;
  #pragma unroll
  for(int j = 0; j < 8; j++){
    float a = cs[c+j], b = csh[c+j];
    float mean_r = s[j]/cnt;
    float var_r  = fmaxf(q[j]/cnt - mean_r*mean_r, 0.f);
    float meanp = a*mean_r + b;
    float mnp = (a >= 0.f) ? a*mn[j]+b : a*mx[j]+b;
    float mxp = (a >= 0.f) ? a*mx[j]+b : a*mn[j]+b;
    float sdp = sqrtf(a*a*var_r + EPSV);
    if(end <= beg){ meanp = 0.f; mnp = 0.f; mxp = 0.f; sdp = sqrtf(EPSV); }
    vm[j] = (_Float16)meanp; vn[j] = (_Float16)mnp;
    vx[j] = (_Float16)mxp;   vs[j] = (_Float16)sdp;
  }

  _Float16* dst = aggs + (size_t)(c>>6)*aggN + (size_t)n*256 + (c & 63);
  *(h8*)(dst)       = vm;
  *(h8*)(dst + 64)  = vn;
  *(h8*)(dst + 128) = vx;
  *(h8*)(dst + 192) = vs;
}

// ---------------- fused W pre-pack (all layers/chunks, one kernel) ----------------
// Per chunk slab: Wp[kb=K/32][nt=o/16][lane=64][j=8]; row perm: k<64 -> j0+k ;
// [64,320)->(1+q)d+j0+r ; [320,576)->(5+q)d+j0+r ; [576,832)->(9+q)d+j0+r

struct PackJob { const float* W; _Float16* dst; int d, o, j0, start; };
struct PackArgs { PackJob job[9]; int total; };

__global__ void k_pack_all(PackArgs a){
  int idx = blockIdx.x*256 + threadIdx.x;
  if(idx >= a.total) return;
  int ji = 0;
  while(ji < 8 && idx >= a.job[ji+1].start) ji++;
  PackJob J = a.job[ji];
  int rel = idx - J.start;
  int j    = rel & 7;
  int lane = (rel >> 3) & 63;
  int rem  = rel >> 9;
  int ntiles = J.o >> 4;
  int kb = rem / ntiles;
  int nt = rem - kb*ntiles;
  int k = kb*32 + (lane>>4)*8 + j;
  int n = nt*16 + (lane&15);
  int srcrow;
  if(k < 64)       srcrow = J.j0 + k;
  else if(k < 320){ int t=k-64;  srcrow = (1+(t>>6))*J.d + J.j0 + (t&63); }
  else if(k < 576){ int t=k-320; srcrow = (5+(t>>6))*J.d + J.j0 + (t&63); }
  else            { int t=k-576; srcrow = (9+(t>>6))*J.d + J.j0 + (t&63); }
  J.dst[rel] = (_Float16)J.W[(size_t)srcrow*J.o + n];
}

// ---------------- fused MFMA layer GEMM + shuffle-reduced BN-stats epilogue ----------------
// r9/r13 geometry: 4 waves x 32 rows = 128 rows, 64 cols. x-phase A-frags get
// BN affine; epilogue: +bias, ReLU, fp16 store, then per-column sum/sumsq via
// shfl_xor(16/32) q-fold (q==0 lanes only touch LDS) -> 64 global atomics/blk.

__global__ __launch_bounds__(256) void k_mfma_fused(
    const _Float16* __restrict__ actIn, int d, int nch,
    const _Float16* __restrict__ aggs,          // [nch][NN][256], already affine'd
    const float* __restrict__ amp, const float* __restrict__ att,
    const _Float16* __restrict__ cs16, const _Float16* __restrict__ csh16,
    const _Float16* __restrict__ Wp, int o,     // [nch][832*o]
    const float* __restrict__ bias,
    _Float16* __restrict__ out,                 // [NN][o], relu'd pre-BN
    float* __restrict__ colsum, float* __restrict__ colss)
{
  __shared__ float redS[64], redQ[64];
  int tid  = threadIdx.x;
  int wv   = tid >> 6;
  int lane = tid & 63;
  int mi   = lane & 15;
  int q    = lane >> 4;
  int m0   = blockIdx.y * 128 + wv * 32;
  int c0   = blockIdx.x * 64;
  int ntiles = o >> 4;
  int nt0  = blockIdx.x * 4;

  if(tid < 64){ redS[tid] = 0.f; redQ[tid] = 0.f; }

  int mrow[2];
  mrow[0] = min(m0 + mi,      NN-1);
  mrow[1] = min(m0 + 16 + mi, NN-1);
  _Float16 am16[2] = { (_Float16)amp[mrow[0]], (_Float16)amp[mrow[1]] };
  _Float16 at16[2] = { (_Float16)att[mrow[0]], (_Float16)att[mrow[1]] };
  const _Float16* hAb[2];
  const _Float16* agb[2];
  hAb[0] = actIn + (size_t)mrow[0]*d + q*8;
  hAb[1] = actIn + (size_t)mrow[1]*d + q*8;
  agb[0] = aggs + (size_t)mrow[0]*256 + q*8;
  agb[1] = aggs + (size_t)mrow[1]*256 + q*8;

  f4 acc[2][4] = {};
  const size_t aggN = (size_t)NN*256;

  for(int c = 0; c < nch; c++){
    const _Float16* Wpc = Wp + (size_t)c*832*o;
    auto bfrag = [&](int kb, int nn) -> h8 {
      return *(const h8*)(Wpc + (((size_t)kb*ntiles + nt0 + nn)*64 + lane)*8);
    };

    // ---- A fragments (prefetch): x-phase with BN affine, aggs raw ----
    h8 ax[2][2];
    h8 ag[8][2];
    #pragma unroll
    for(int kb = 0; kb < 2; kb++){
      h8 sc = *(const h8*)(cs16  + c*64 + kb*32 + q*8);
      h8 sh = *(const h8*)(csh16 + c*64 + kb*32 + q*8);
      #pragma unroll
      for(int t = 0; t < 2; t++){
        h8 a = *(const h8*)(hAb[t] + c*64 + kb*32);
        ax[kb][t] = a*sc + sh;
      }
    }
    #pragma unroll
    for(int idx = 0; idx < 8; idx++)
      #pragma unroll
      for(int t = 0; t < 2; t++)
        ag[idx][t] = *(const h8*)(agb[t] + (size_t)c*aggN + idx*32);

    // ---- phase X: kb = 0,1 ----
    #pragma unroll
    for(int kb = 0; kb < 2; kb++)
      #pragma unroll
      for(int t = 0; t < 2; t++)
        #pragma unroll
        for(int nn = 0; nn < 4; nn++)
          acc[t][nn] = __builtin_amdgcn_mfma_f32_16x16x32_f16(ax[kb][t], bfrag(kb,nn), acc[t][nn], 0,0,0);

    // ---- aggs phases: plain / amp-scaled / att-scaled ----
    #pragma unroll
    for(int idx = 0; idx < 8; idx++){
      #pragma unroll
      for(int t = 0; t < 2; t++){
        h8 apl = ag[idx][t];
        h8 aam = apl * am16[t];
        h8 aat = apl * at16[t];
        #pragma unroll
        for(int nn = 0; nn < 4; nn++){
          acc[t][nn] = __builtin_amdgcn_mfma_f32_16x16x32_f16(apl, bfrag(2+idx,  nn), acc[t][nn], 0,0,0);
          acc[t][nn] = __builtin_amdgcn_mfma_f32_16x16x32_f16(aam, bfrag(10+idx, nn), acc[t][nn], 0,0,0);
          acc[t][nn] = __builtin_amdgcn_mfma_f32_16x16x32_f16(aat, bfrag(18+idx, nn), acc[t][nn], 0,0,0);
        }
      }
    }
  }

  __syncthreads();   // redS/redQ zero-init visible

  // ---- epilogue: +bias, ReLU, store, stats via q-fold shuffles ----
  #pragma unroll
  for(int nn = 0; nn < 4; nn++){
    int n = c0 + nn*16 + mi;
    float bv = bias[n];
    float ps = 0.f, pq = 0.f;
    #pragma unroll
    for(int t = 0; t < 2; t++){
      #pragma unroll
      for(int r = 0; r < 4; r++){
        int m = m0 + t*16 + q*4 + r;
        if(m < NN){
          float v = fmaxf(bv + acc[t][nn][r], 0.f);
          out[(size_t)m*o + n] = (_Float16)v;
          ps += v; pq += v*v;
        }
      }
    }
    // fold the 4 q-groups (same column n across q): xor-16 then xor-32
    ps += __shfl_xor(ps, 16); pq += __shfl_xor(pq, 16);
    ps += __shfl_xor(ps, 32); pq += __shfl_xor(pq, 32);
    if(q == 0){
      atomicAdd(&redS[nn*16 + mi], ps);
      atomicAdd(&redQ[nn*16 + mi], pq);
    }
  }
  __syncthreads();
  if(tid < 64){
    atomicAdd(&colsum[c0 + tid], redS[tid]);
    atomicAdd(&colss[c0 + tid],  redQ[tid]);
  }
}

// ---------------- classifier (applies final BN affine on load) ----------------

__global__ __launch_bounds__(256) void k_cls(const _Float16* __restrict__ h,
    const float* __restrict__ cs, const float* __restrict__ csh,
    const float* __restrict__ Wc, const float* __restrict__ bc,
    float* __restrict__ out){
  __shared__ float w[640];
  __shared__ float bb[16];
  __shared__ float sca[64], shb[64];
  int tid = threadIdx.x;
  for(int i = tid; i < 640; i += 256) w[i] = Wc[i];
  if(tid < 10) bb[tid] = bc[tid];
  if(tid < 64){ sca[tid] = cs[tid]; shb[tid] = csh[tid]; }
  __syncthreads();
  int idx = blockIdx.x*256 + tid;
  int n = idx >> 4;
  int c = idx & 15;
  if(n < NN && c < 10){
    float acc = bb[c];
    const _Float16* hp = h + (size_t)n*64;
    #pragma unroll
    for(int k = 0; k < 64; k++)
      acc += ((float)hp[k]*sca[k] + shb[k]) * w[k*10 + c];
    out[(size_t)n*10 + c] = acc;
  }
}

// ---------------- launch ----------------

extern "C" void kernel_launch(void* const* d_in, const int* in_sizes, int n_in,
                              void* d_out, int out_size, void* d_ws, size_t ws_size,
                              hipStream_t stream){
  const float* x = (const float*)d_in[0];
  const int* edge = (const int*)d_in[1];
  const int* esrc = edge;
  const int* edst = edge + NE;
  const float* W[4]  = {(const float*)d_in[2],  (const float*)d_in[6],
                        (const float*)d_in[10], (const float*)d_in[14]};
  const float* bb[4] = {(const float*)d_in[3],  (const float*)d_in[7],
                        (const float*)d_in[11], (const float*)d_in[15]};
  const float* gm[4] = {(const float*)d_in[4],  (const float*)d_in[8],
                        (const float*)d_in[12], (const float*)d_in[16]};
  const float* bt[4] = {(const float*)d_in[5],  (const float*)d_in[9],
                        (const float*)d_in[13], (const float*)d_in[17]};
  const float* Wc = (const float*)d_in[18];
  const float* bc = (const float*)d_in[19];
  (void)in_sizes; (void)n_in; (void)out_size; (void)ws_size;

  // workspace carve (~158 MB; proven-safe envelope)
  char* p = (char*)d_ws;
  auto alloc = [&](size_t bytes)->char*{
    char* r = p; p += (bytes + 255) & ~(size_t)255; return r;
  };
  _Float16* act0 = (_Float16*)alloc((size_t)NN*256*2);   // 25.6 MB
  _Float16* act1 = (_Float16*)alloc((size_t)NN*256*2);   // 25.6 MB
  _Float16* aggs = (_Float16*)alloc((size_t)4*NN*256*2); // 102.4 MB: [chunk][N][256]
  int*   deg    = (int*)  alloc((size_t)NN*4);
  float* logdeg = (float*)alloc((size_t)NN*4);
  float* amp    = (float*)alloc((size_t)NN*4);
  float* att    = (float*)alloc((size_t)NN*4);
  int*   rowptr = (int*)  alloc((size_t)(NN+1)*4);
  int*   cursor = (int*)  alloc((size_t)NN*4);
  int*   colidx = (int*)  alloc((size_t)NE*4);
  int*   bsum   = (int*)  alloc((size_t)(NB+1)*4);
  float* colsumL= (float*)alloc(4*256*4);   // per-layer BN partials
  float* colssL = (float*)alloc(4*256*4);
  float* dsum   = (float*)alloc(256);
  // BN coefficient double-buffers (fp32 + fp16)
  float*    csA  = (float*)   alloc(256*4);
  float*    cshA = (float*)   alloc(256*4);
  float*    csB  = (float*)   alloc(256*4);
  float*    cshB = (float*)   alloc(256*4);
  _Float16* cs16A  = (_Float16*)alloc(256*2);
  _Float16* csh16A = (_Float16*)alloc(256*2);
  _Float16* cs16B  = (_Float16*)alloc(256*2);
  _Float16* csh16B = (_Float16*)alloc(256*2);

  const int din[4]  = {64, 128, 256, 128};
  const int dto[4]  = {128, 256, 128, 64};
  const size_t aggN = (size_t)NN*256;      // halves per chunk slab
  _Float16* WpL[4];
  PackArgs pa; int pj = 0, poff = 0;
  for(int l = 0; l < 4; l++){
    int nch = din[l]/64;
    WpL[l] = (_Float16*)alloc((size_t)nch*832*dto[l]*2);
    for(int c = 0; c < nch; c++){
      pa.job[pj] = { W[l], WpL[l] + (size_t)c*832*dto[l], din[l], dto[l], c*64, poff };
      poff += 832*dto[l]; pj++;
    }
  }
  pa.total = poff;

  hipMemsetAsync(deg, 0, (size_t)NN*4, stream);
  hipMemsetAsync(dsum, 0, 4, stream);
  hipMemsetAsync(colsumL, 0, 4*256*4, stream);
  hipMemsetAsync(colssL,  0, 4*256*4, stream);

  k_pack_all<<<(pa.total+255)/256, 256, 0, stream>>>(pa);
  k_deg     <<<(NE+255)/256, 256, 0, stream>>>(edst, deg);
  k_logdeg  <<<(NN+255)/256, 256, 0, stream>>>(deg, logdeg, dsum);
  k_scalers <<<(NN+255)/256, 256, 0, stream>>>(logdeg, dsum, amp, att);
  k_scan1   <<<NB, 1024, 0, stream>>>(deg, rowptr, bsum);
  k_scan2   <<<1, 64, 0, stream>>>(bsum);
  k_scan3   <<<(NN+256)/256, 256, 0, stream>>>(rowptr, cursor, bsum);
  k_fill    <<<(NE+255)/256, 256, 0, stream>>>(esrc, edst, cursor, colidx);
  k_cvtx    <<<(NN*64+255)/256, 256, 0, stream>>>(x, act0);
  k_coef_id <<<1, 256, 0, stream>>>(csA, cshA, cs16A, csh16A);

  _Float16* actIn = act0;  _Float16* actOut = act1;
  float *csI = csA, *cshI = cshA, *csO = csB, *cshO = cshB;
  _Float16 *cs16I = cs16A, *csh16I = csh16A, *cs16O = cs16B, *csh16O = csh16B;

  for(int l = 0; l < 4; l++){
    int d = din[l], o = dto[l];
    int nch = d / 64;
    int npb = (64 / (d >> 3)) * 4;          // nodes per block in k_agg8
    k_agg8<<<(NN+npb-1)/npb, 256, 0, stream>>>(actIn, d, rowptr, colidx,
                                               csI, cshI, aggs, aggN);
    dim3 g(o/64, (NN+127)/128);
    k_mfma_fused<<<g, 256, 0, stream>>>(actIn, d, nch, aggs, amp, att,
                                        cs16I, csh16I, WpL[l], o, bb[l], actOut,
                                        colsumL + l*256, colssL + l*256);
    k_bn_coef<<<1, 256, 0, stream>>>(colsumL + l*256, colssL + l*256, gm[l], bt[l], o,
                                     csO, cshO, cs16O, csh16O);
    // swap activation and coefficient buffers
    _Float16* ta = actIn; actIn = actOut; actOut = ta;
    float* tf;
    tf = csI;  csI = csO;  csO = tf;
    tf = cshI; cshI = cshO; cshO = tf;
    _Float16* th;
    th = cs16I;  cs16I = cs16O;  cs16O = th;
    th = csh16I; csh16I = csh16O; csh16O = th;
  }
  k_cls<<<(NN*16+255)/256, 256, 0, stream>>>(actIn, csI, cshI, Wc, bc, (float*)d_out);
}

// Round 16
// 695.864 us; speedup vs baseline: 1.2666x; 1.0122x over previous
//
#include <hip/hip_runtime.h>
#include <hip/hip_bf16.h>

#define NN 50000
#define NE 800000
#define EPSV 1e-5f
#define NB 49   // scan blocks: ceil(NN/1024)

typedef _Float16 h8 __attribute__((ext_vector_type(8)));
typedef float    f4 __attribute__((ext_vector_type(4)));

// ---------------- graph preprocessing ----------------

__global__ void k_deg(const int* __restrict__ dst, int* __restrict__ deg){
  int e = blockIdx.x*blockDim.x + threadIdx.x;
  if(e < NE) atomicAdd(&deg[dst[e]], 1);
}

__global__ void k_logdeg(const int* __restrict__ deg, float* __restrict__ logdeg,
                         float* __restrict__ dsum){
  int i = blockIdx.x*blockDim.x + threadIdx.x;
  float v = 0.f;
  if(i < NN){ v = log1pf((float)deg[i]); logdeg[i] = v; }
  __shared__ float sh[256];
  sh[threadIdx.x] = v; __syncthreads();
  for(int off=128; off>0; off>>=1){
    if(threadIdx.x < off) sh[threadIdx.x] += sh[threadIdx.x+off];
    __syncthreads();
  }
  if(threadIdx.x == 0) atomicAdd(dsum, sh[0]);
}

__global__ void k_scalers(const float* __restrict__ logdeg, const float* __restrict__ dsum,
                          float* __restrict__ amp, float* __restrict__ att){
  int i = blockIdx.x*blockDim.x + threadIdx.x;
  if(i >= NN) return;
  float delta = dsum[0] / (float)NN;
  float ld = logdeg[i];
  amp[i] = ld / delta;
  att[i] = (ld > 0.f) ? (delta / fmaxf(ld, 1e-6f)) : 1.f;
}

// 3-phase parallel exclusive scan of deg -> rowptr (+cursor copy)
__global__ void k_scan1(const int* __restrict__ deg, int* __restrict__ rowptr,
                        int* __restrict__ bsum){
  __shared__ int buf[1024];
  int tid = threadIdx.x;
  int i = blockIdx.x*1024 + tid;
  int v = (i < NN) ? deg[i] : 0;
  buf[tid] = v; __syncthreads();
  for(int off=1; off<1024; off<<=1){
    int t = (tid >= off) ? buf[tid-off] : 0;
    __syncthreads();
    buf[tid] += t;
    __syncthreads();
  }
  if(i < NN) rowptr[i] = buf[tid] - v;
  if(tid == 1023) bsum[blockIdx.x] = buf[1023];
}

__global__ void k_scan2(int* __restrict__ bsum){
  if(threadIdx.x == 0){
    int s = 0;
    for(int b = 0; b < NB; b++){ int t = bsum[b]; bsum[b] = s; s += t; }
    bsum[NB] = s;
  }
}

__global__ void k_scan3(int* __restrict__ rowptr, int* __restrict__ cursor,
                        const int* __restrict__ bsum){
  int i = blockIdx.x*256 + threadIdx.x;
  if(i < NN){
    int v = rowptr[i] + bsum[i >> 10];
    rowptr[i] = v; cursor[i] = v;
  }
  if(i == NN) rowptr[NN] = bsum[NB];
}

__global__ void k_fill(const int* __restrict__ src, const int* __restrict__ dst,
                       int* __restrict__ cursor, int* __restrict__ colidx){
  int e = blockIdx.x*blockDim.x + threadIdx.x;
  if(e < NE){
    int pos = atomicAdd(&cursor[dst[e]], 1);
    colidx[pos] = src[e];
  }
}

__global__ void k_cvtx(const float* __restrict__ x, _Float16* __restrict__ act){
  int i = blockIdx.x*256 + threadIdx.x;
  if(i < NN*64) act[i] = (_Float16)x[i];
}

// identity BN coefficients for layer 1
__global__ void k_coef_id(float* __restrict__ cs, float* __restrict__ csh,
                          _Float16* __restrict__ cs16, _Float16* __restrict__ csh16){
  int c = threadIdx.x;
  cs[c] = 1.f; csh[c] = 0.f;
  cs16[c] = (_Float16)1.f; csh16[c] = (_Float16)0.f;
}

// BN coefficients from stats: v' = a*v + b with a=inv*gamma, b=beta-mean*a
__global__ void k_bn_coef(const float* __restrict__ colsum, const float* __restrict__ colss,
                          const float* __restrict__ gamma, const float* __restrict__ beta,
                          int dout, float* __restrict__ cs, float* __restrict__ csh,
                          _Float16* __restrict__ cs16, _Float16* __restrict__ csh16){
  int c = threadIdx.x;
  if(c >= dout) return;
  float mean = colsum[c] / (float)NN;
  float var  = colss[c] / (float)NN - mean*mean;
  float inv  = rsqrtf(fmaxf(var, 0.f) + EPSV);
  float a = inv * gamma[c];
  float b = beta[c] - mean * a;
  cs[c] = a; csh[c] = b;
  cs16[c] = (_Float16)a; csh16[c] = (_Float16)b;
}

// ---------------- aggregation (templated on D): 8 cols/lane, 16 B loads ----------------
// Reads RAW act; applies per-column affine (a,b) in the epilogue:
// mean'=a*mean+b ; min/max swap on a<0 ; std'=sqrt(a^2*var+eps).
// aggs[chunk][n*256 + {0,64,128,192} + cl] = mean|min|max|std

template<int D>
__global__ __launch_bounds__(256) void k_agg8(
    const _Float16* __restrict__ act,
    const int* __restrict__ rowptr, const int* __restrict__ colidx,
    const float* __restrict__ cs, const float* __restrict__ csh,
    _Float16* __restrict__ aggs, size_t aggN)
{
  constexpr int LPN = D >> 3;       // lanes per node: 8/16/32
  constexpr int NPW = 64 / LPN;     // nodes per wave: 8/4/2
  int wv = threadIdx.x >> 6, lane = threadIdx.x & 63;
  int n = blockIdx.x*(NPW*4) + wv*NPW + (lane / LPN);
  int c = (lane % LPN) * 8;         // 8 adjacent feature cols
  if(n >= NN) return;
  int beg = rowptr[n], end = rowptr[n+1];
  const _Float16* hp = act + c;

  float s[8], q[8], mn[8], mx[8];
  #pragma unroll
  for(int j = 0; j < 8; j++){ s[j]=0.f; q[j]=0.f; mn[j]=INFINITY; mx[j]=-INFINITY; }

#define ACC8(v) { _Pragma("unroll") for(int j=0;j<8;j++){ float a=(float)(v)[j]; \
    s[j]+=a; q[j]+=a*a; mn[j]=fminf(mn[j],a); mx[j]=fmaxf(mx[j],a); } }

  int e = beg;
  for(; e+8 <= end; e+=8){
    int i0=colidx[e],   i1=colidx[e+1], i2=colidx[e+2], i3=colidx[e+3];
    int i4=colidx[e+4], i5=colidx[e+5], i6=colidx[e+6], i7=colidx[e+7];
    h8 v0 = *(const h8*)(hp + (size_t)i0*D);
    h8 v1 = *(const h8*)(hp + (size_t)i1*D);
    h8 v2 = *(const h8*)(hp + (size_t)i2*D);
    h8 v3 = *(const h8*)(hp + (size_t)i3*D);
    h8 v4 = *(const h8*)(hp + (size_t)i4*D);
    h8 v5 = *(const h8*)(hp + (size_t)i5*D);
    h8 v6 = *(const h8*)(hp + (size_t)i6*D);
    h8 v7 = *(const h8*)(hp + (size_t)i7*D);
    ACC8(v0) ACC8(v1) ACC8(v2) ACC8(v3) ACC8(v4) ACC8(v5) ACC8(v6) ACC8(v7)
  }
  for(; e+4 <= end; e+=4){
    int i0=colidx[e], i1=colidx[e+1], i2=colidx[e+2], i3=colidx[e+3];
    h8 v0 = *(const h8*)(hp + (size_t)i0*D);
    h8 v1 = *(const h8*)(hp + (size_t)i1*D);
    h8 v2 = *(const h8*)(hp + (size_t)i2*D);
    h8 v3 = *(const h8*)(hp + (size_t)i3*D);
    ACC8(v0) ACC8(v1) ACC8(v2) ACC8(v3)
  }
  for(; e < end; e++){
    h8 v = *(const h8*)(hp + (size_t)colidx[e]*D);
    ACC8(v)
  }
#undef ACC8

  float cnt = (end>beg) ? (float)(end-beg) : 1.f;
  h8 vm, vn, vx, vs;
  #pragma unroll
  for(int j = 0; j < 8; j++){
    float a = cs[c+j], b = csh[c+j];
    float mean_r = s[j]/cnt;
    float var_r  = fmaxf(q[j]/cnt - mean_r*mean_r, 0.f);
    float meanp = a*mean_r + b;
    float mnp = (a >= 0.f) ? a*mn[j]+b : a*mx[j]+b;
    float mxp = (a >= 0.f) ? a*mx[j]+b : a*mn[j]+b;
    float sdp = sqrtf(a*a*var_r + EPSV);
    if(end <= beg){ meanp = 0.f; mnp = 0.f; mxp = 0.f; sdp = sqrtf(EPSV); }
    vm[j] = (_Float16)meanp; vn[j] = (_Float16)mnp;
    vx[j] = (_Float16)mxp;   vs[j] = (_Float16)sdp;
  }

  _Float16* dst = aggs + (size_t)(c>>6)*aggN + (size_t)n*256 + (c & 63);
  *(h8*)(dst)       = vm;
  *(h8*)(dst + 64)  = vn;
  *(h8*)(dst + 128) = vx;
  *(h8*)(dst + 192) = vs;
}

// ---------------- fused W pre-pack (all layers/chunks, one kernel) ----------------
// Per chunk slab: Wp[kb=K/32][nt=o/16][lane=64][j=8]; row perm: k<64 -> j0+k ;
// [64,320)->(1+q)d+j0+r ; [320,576)->(5+q)d+j0+r ; [576,832)->(9+q)d+j0+r

struct PackJob { const float* W; _Float16* dst; int d, o, j0, start; };
struct PackArgs { PackJob job[9]; int total; };

__global__ void k_pack_all(PackArgs a){
  int idx = blockIdx.x*256 + threadIdx.x;
  if(idx >= a.total) return;
  int ji = 0;
  while(ji < 8 && idx >= a.job[ji+1].start) ji++;
  PackJob J = a.job[ji];
  int rel = idx - J.start;
  int j    = rel & 7;
  int lane = (rel >> 3) & 63;
  int rem  = rel >> 9;
  int ntiles = J.o >> 4;
  int kb = rem / ntiles;
  int nt = rem - kb*ntiles;
  int k = kb*32 + (lane>>4)*8 + j;
  int n = nt*16 + (lane&15);
  int srcrow;
  if(k < 64)       srcrow = J.j0 + k;
  else if(k < 320){ int t=k-64;  srcrow = (1+(t>>6))*J.d + J.j0 + (t&63); }
  else if(k < 576){ int t=k-320; srcrow = (5+(t>>6))*J.d + J.j0 + (t&63); }
  else            { int t=k-576; srcrow = (9+(t>>6))*J.d + J.j0 + (t&63); }
  J.dst[rel] = (_Float16)J.W[(size_t)srcrow*J.o + n];
}

// ---------------- fused MFMA layer GEMM (templated NCH, fully unrolled K) ----------------
// r9 geometry: 4 waves x 32 rows = 128 rows, 64 cols. Chunk loop fully
// unrolled so the compiler can hoist chunk c+1 A-loads under chunk c MFMAs.
// Epilogue: +bias, ReLU, fp16 store, shuffle-reduced BN stats.

template<int NCH>
__global__ __launch_bounds__(256) void k_mfma_fused(
    const _Float16* __restrict__ actIn,
    const _Float16* __restrict__ aggs,          // [NCH][NN][256], already affine'd
    const float* __restrict__ amp, const float* __restrict__ att,
    const _Float16* __restrict__ cs16, const _Float16* __restrict__ csh16,
    const _Float16* __restrict__ Wp, int o,     // [NCH][832*o]
    const float* __restrict__ bias,
    _Float16* __restrict__ out,                 // [NN][o], relu'd pre-BN
    float* __restrict__ colsum, float* __restrict__ colss)
{
  constexpr int D = NCH * 64;
  __shared__ float redS[64], redQ[64];
  int tid  = threadIdx.x;
  int wv   = tid >> 6;
  int lane = tid & 63;
  int mi   = lane & 15;
  int q    = lane >> 4;
  int m0   = blockIdx.y * 128 + wv * 32;
  int c0   = blockIdx.x * 64;
  int ntiles = o >> 4;
  int nt0  = blockIdx.x * 4;

  if(tid < 64){ redS[tid] = 0.f; redQ[tid] = 0.f; }

  int mrow[2];
  mrow[0] = min(m0 + mi,      NN-1);
  mrow[1] = min(m0 + 16 + mi, NN-1);
  _Float16 am16[2] = { (_Float16)amp[mrow[0]], (_Float16)amp[mrow[1]] };
  _Float16 at16[2] = { (_Float16)att[mrow[0]], (_Float16)att[mrow[1]] };
  const _Float16* hAb[2];
  const _Float16* agb[2];
  hAb[0] = actIn + (size_t)mrow[0]*D + q*8;
  hAb[1] = actIn + (size_t)mrow[1]*D + q*8;
  agb[0] = aggs + (size_t)mrow[0]*256 + q*8;
  agb[1] = aggs + (size_t)mrow[1]*256 + q*8;

  f4 acc[2][4] = {};
  const size_t aggN = (size_t)NN*256;

  #pragma unroll
  for(int c = 0; c < NCH; c++){
    const _Float16* Wpc = Wp + (size_t)c*832*o;
    auto bfrag = [&](int kb, int nn) -> h8 {
      return *(const h8*)(Wpc + (((size_t)kb*ntiles + nt0 + nn)*64 + lane)*8);
    };

    // ---- A fragments (prefetch): x-phase with BN affine, aggs raw ----
    h8 ax[2][2];
    h8 ag[8][2];
    #pragma unroll
    for(int kb = 0; kb < 2; kb++){
      h8 sc = *(const h8*)(cs16  + c*64 + kb*32 + q*8);
      h8 sh = *(const h8*)(csh16 + c*64 + kb*32 + q*8);
      #pragma unroll
      for(int t = 0; t < 2; t++){
        h8 a = *(const h8*)(hAb[t] + c*64 + kb*32);
        ax[kb][t] = a*sc + sh;
      }
    }
    #pragma unroll
    for(int idx = 0; idx < 8; idx++)
      #pragma unroll
      for(int t = 0; t < 2; t++)
        ag[idx][t] = *(const h8*)(agb[t] + (size_t)c*aggN + idx*32);

    // ---- phase X: kb = 0,1 ----
    #pragma unroll
    for(int kb = 0; kb < 2; kb++)
      #pragma unroll
      for(int t = 0; t < 2; t++)
        #pragma unroll
        for(int nn = 0; nn < 4; nn++)
          acc[t][nn] = __builtin_amdgcn_mfma_f32_16x16x32_f16(ax[kb][t], bfrag(kb,nn), acc[t][nn], 0,0,0);

    // ---- aggs phases: plain / amp-scaled / att-scaled ----
    #pragma unroll
    for(int idx = 0; idx < 8; idx++){
      #pragma unroll
      for(int t = 0; t < 2; t++){
        h8 apl = ag[idx][t];
        h8 aam = apl * am16[t];
        h8 aat = apl * at16[t];
        #pragma unroll
        for(int nn = 0; nn < 4; nn++){
          acc[t][nn] = __builtin_amdgcn_mfma_f32_16x16x32_f16(apl, bfrag(2+idx,  nn), acc[t][nn], 0,0,0);
          acc[t][nn] = __builtin_amdgcn_mfma_f32_16x16x32_f16(aam, bfrag(10+idx, nn), acc[t][nn], 0,0,0);
          acc[t][nn] = __builtin_amdgcn_mfma_f32_16x16x32_f16(aat, bfrag(18+idx, nn), acc[t][nn], 0,0,0);
        }
      }
    }
  }

  __syncthreads();   // redS/redQ zero-init visible

  // ---- epilogue: +bias, ReLU, store, stats via q-fold shuffles ----
  #pragma unroll
  for(int nn = 0; nn < 4; nn++){
    int n = c0 + nn*16 + mi;
    float bv = bias[n];
    float ps = 0.f, pq = 0.f;
    #pragma unroll
    for(int t = 0; t < 2; t++){
      #pragma unroll
      for(int r = 0; r < 4; r++){
        int m = m0 + t*16 + q*4 + r;
        if(m < NN){
          float v = fmaxf(bv + acc[t][nn][r], 0.f);
          out[(size_t)m*o + n] = (_Float16)v;
          ps += v; pq += v*v;
        }
      }
    }
    ps += __shfl_xor(ps, 16); pq += __shfl_xor(pq, 16);
    ps += __shfl_xor(ps, 32); pq += __shfl_xor(pq, 32);
    if(q == 0){
      atomicAdd(&redS[nn*16 + mi], ps);
      atomicAdd(&redQ[nn*16 + mi], pq);
    }
  }
  __syncthreads();
  if(tid < 64){
    atomicAdd(&colsum[c0 + tid], redS[tid]);
    atomicAdd(&colss[c0 + tid],  redQ[tid]);
  }
}

// ---------------- classifier (applies final BN affine on load) ----------------

__global__ __launch_bounds__(256) void k_cls(const _Float16* __restrict__ h,
    const float* __restrict__ cs, const float* __restrict__ csh,
    const float* __restrict__ Wc, const float* __restrict__ bc,
    float* __restrict__ out){
  __shared__ float w[640];
  __shared__ float bb[16];
  __shared__ float sca[64], shb[64];
  int tid = threadIdx.x;
  for(int i = tid; i < 640; i += 256) w[i] = Wc[i];
  if(tid < 10) bb[tid] = bc[tid];
  if(tid < 64){ sca[tid] = cs[tid]; shb[tid] = csh[tid]; }
  __syncthreads();
  int idx = blockIdx.x*256 + tid;
  int n = idx >> 4;
  int c = idx & 15;
  if(n < NN && c < 10){
    float acc = bb[c];
    const _Float16* hp = h + (size_t)n*64;
    #pragma unroll
    for(int k = 0; k < 64; k++)
      acc += ((float)hp[k]*sca[k] + shb[k]) * w[k*10 + c];
    out[(size_t)n*10 + c] = acc;
  }
}

// ---------------- launch ----------------

extern "C" void kernel_launch(void* const* d_in, const int* in_sizes, int n_in,
                              void* d_out, int out_size, void* d_ws, size_t ws_size,
                              hipStream_t stream){
  const float* x = (const float*)d_in[0];
  const int* edge = (const int*)d_in[1];
  const int* esrc = edge;
  const int* edst = edge + NE;
  const float* W[4]  = {(const float*)d_in[2],  (const float*)d_in[6],
                        (const float*)d_in[10], (const float*)d_in[14]};
  const float* bb[4] = {(const float*)d_in[3],  (const float*)d_in[7],
                        (const float*)d_in[11], (const float*)d_in[15]};
  const float* gm[4] = {(const float*)d_in[4],  (const float*)d_in[8],
                        (const float*)d_in[12], (const float*)d_in[16]};
  const float* bt[4] = {(const float*)d_in[5],  (const float*)d_in[9],
                        (const float*)d_in[13], (const float*)d_in[17]};
  const float* Wc = (const float*)d_in[18];
  const float* bc = (const float*)d_in[19];
  (void)in_sizes; (void)n_in; (void)out_size; (void)ws_size;

  // workspace carve (~158 MB; proven-safe envelope)
  char* p = (char*)d_ws;
  auto alloc = [&](size_t bytes)->char*{
    char* r = p; p += (bytes + 255) & ~(size_t)255; return r;
  };
  _Float16* act0 = (_Float16*)alloc((size_t)NN*256*2);   // 25.6 MB
  _Float16* act1 = (_Float16*)alloc((size_t)NN*256*2);   // 25.6 MB
  _Float16* aggs = (_Float16*)alloc((size_t)4*NN*256*2); // 102.4 MB: [chunk][N][256]
  int*   deg    = (int*)  alloc((size_t)NN*4);
  float* logdeg = (float*)alloc((size_t)NN*4);
  float* amp    = (float*)alloc((size_t)NN*4);
  float* att    = (float*)alloc((size_t)NN*4);
  int*   rowptr = (int*)  alloc((size_t)(NN+1)*4);
  int*   cursor = (int*)  alloc((size_t)NN*4);
  int*   colidx = (int*)  alloc((size_t)NE*4);
  int*   bsum   = (int*)  alloc((size_t)(NB+1)*4);
  float* colsumL= (float*)alloc(4*256*4);   // per-layer BN partials
  float* colssL = (float*)alloc(4*256*4);
  float* dsum   = (float*)alloc(256);
  // BN coefficient double-buffers (fp32 + fp16)
  float*    csA  = (float*)   alloc(256*4);
  float*    cshA = (float*)   alloc(256*4);
  float*    csB  = (float*)   alloc(256*4);
  float*    cshB = (float*)   alloc(256*4);
  _Float16* cs16A  = (_Float16*)alloc(256*2);
  _Float16* csh16A = (_Float16*)alloc(256*2);
  _Float16* cs16B  = (_Float16*)alloc(256*2);
  _Float16* csh16B = (_Float16*)alloc(256*2);

  const int din[4]  = {64, 128, 256, 128};
  const int dto[4]  = {128, 256, 128, 64};
  const size_t aggN = (size_t)NN*256;      // halves per chunk slab
  _Float16* WpL[4];
  PackArgs pa; int pj = 0, poff = 0;
  for(int l = 0; l < 4; l++){
    int nch = din[l]/64;
    WpL[l] = (_Float16*)alloc((size_t)nch*832*dto[l]*2);
    for(int c = 0; c < nch; c++){
      pa.job[pj] = { W[l], WpL[l] + (size_t)c*832*dto[l], din[l], dto[l], c*64, poff };
      poff += 832*dto[l]; pj++;
    }
  }
  pa.total = poff;

  hipMemsetAsync(deg, 0, (size_t)NN*4, stream);
  hipMemsetAsync(dsum, 0, 4, stream);
  hipMemsetAsync(colsumL, 0, 4*256*4, stream);
  hipMemsetAsync(colssL,  0, 4*256*4, stream);

  k_pack_all<<<(pa.total+255)/256, 256, 0, stream>>>(pa);
  k_deg     <<<(NE+255)/256, 256, 0, stream>>>(edst, deg);
  k_logdeg  <<<(NN+255)/256, 256, 0, stream>>>(deg, logdeg, dsum);
  k_scalers <<<(NN+255)/256, 256, 0, stream>>>(logdeg, dsum, amp, att);
  k_scan1   <<<NB, 1024, 0, stream>>>(deg, rowptr, bsum);
  k_scan2   <<<1, 64, 0, stream>>>(bsum);
  k_scan3   <<<(NN+256)/256, 256, 0, stream>>>(rowptr, cursor, bsum);
  k_fill    <<<(NE+255)/256, 256, 0, stream>>>(esrc, edst, cursor, colidx);
  k_cvtx    <<<(NN*64+255)/256, 256, 0, stream>>>(x, act0);
  k_coef_id <<<1, 256, 0, stream>>>(csA, cshA, cs16A, csh16A);

  _Float16* actIn = act0;  _Float16* actOut = act1;
  float *csI = csA, *cshI = cshA, *csO = csB, *cshO = cshB;
  _Float16 *cs16I = cs16A, *csh16I = csh16A, *cs16O = cs16B, *csh16O = csh16B;

  for(int l = 0; l < 4; l++){
    int d = din[l], o = dto[l];
    int npb = (64 / (d >> 3)) * 4;          // nodes per block in k_agg8
    int nagg = (NN + npb - 1) / npb;
    dim3 g(o/64, (NN+127)/128);
    float* csum = colsumL + l*256;
    float* csq  = colssL + l*256;
    switch(d){
      case 64:
        k_agg8<64><<<nagg, 256, 0, stream>>>(actIn, rowptr, colidx, csI, cshI, aggs, aggN);
        k_mfma_fused<1><<<g, 256, 0, stream>>>(actIn, aggs, amp, att, cs16I, csh16I,
                                               WpL[l], o, bb[l], actOut, csum, csq);
        break;
      case 128:
        k_agg8<128><<<nagg, 256, 0, stream>>>(actIn, rowptr, colidx, csI, cshI, aggs, aggN);
        k_mfma_fused<2><<<g, 256, 0, stream>>>(actIn, aggs, amp, att, cs16I, csh16I,
                                               WpL[l], o, bb[l], actOut, csum, csq);
        break;
      default:
        k_agg8<256><<<nagg, 256, 0, stream>>>(actIn, rowptr, colidx, csI, cshI, aggs, aggN);
        k_mfma_fused<4><<<g, 256, 0, stream>>>(actIn, aggs, amp, att, cs16I, csh16I,
                                               WpL[l], o, bb[l], actOut, csum, csq);
        break;
    }
    k_bn_coef<<<1, 256, 0, stream>>>(csum, csq, gm[l], bt[l], o,
                                     csO, cshO, cs16O, csh16O);
    // swap activation and coefficient buffers
    _Float16* ta = actIn; actIn = actOut; actOut = ta;
    float* tf;
    tf = csI;  csI = csO;  csO = tf;
    tf = cshI; cshI = cshO; cshO = tf;
    _Float16* th;
    th = cs16I;  cs16I = cs16O;  cs16O = th;
    th = csh16I; csh16I = csh16O; csh16O = th;
  }
  k_cls<<<(NN*16+255)/256, 256, 0, stream>>>(actIn, csI, cshI, Wc, bc, (float*)d_out);
}